// Round 6
// baseline (1232.351 us; speedup 1.0000x reference)
//
#include <hip/hip_runtime.h>
#include <math.h>

#define H 256

typedef __attribute__((ext_vector_type(8))) short short8;
typedef __attribute__((ext_vector_type(4))) float f32x4;
typedef __attribute__((ext_vector_type(4))) int int4v;
typedef __attribute__((ext_vector_type(2))) unsigned int uint2v;
typedef unsigned short ushort_t;

__device__ __forceinline__ float bf2f(unsigned short u) {
    union { unsigned int i; float f; } v; v.i = ((unsigned int)u) << 16; return v.f;
}
__device__ __forceinline__ unsigned short f2bf(float f) {
    union { float f; unsigned int i; } v; v.f = f;
    unsigned int r = v.i + 0x7FFFu + ((v.i >> 16) & 1u);   // RNE
    return (unsigned short)(r >> 16);
}
__device__ __forceinline__ void glds16(const void* g, void* l) {
    __builtin_amdgcn_global_load_lds((const __attribute__((address_space(1))) void*)g,
                                     (__attribute__((address_space(3))) void*)l, 16, 0, 0);
}
__device__ __forceinline__ int4v pack_f32x8_bf16(const float* p) {
    float4 f0 = *(const float4*)(p);
    float4 f1 = *(const float4*)(p + 4);
    int4v d;
    d.x = (int)((unsigned)f2bf(f0.x) | ((unsigned)f2bf(f0.y) << 16));
    d.y = (int)((unsigned)f2bf(f0.z) | ((unsigned)f2bf(f0.w) << 16));
    d.z = (int)((unsigned)f2bf(f1.x) | ((unsigned)f2bf(f1.y) << 16));
    d.w = (int)((unsigned)f2bf(f1.z) | ((unsigned)f2bf(f1.w) << 16));
    return d;
}

// ---------------- prep ----------------
__global__ void prep_weights(const float* __restrict__ Wm, const float* __restrict__ Wg,
                             const float* __restrict__ Wu,
                             ushort_t* __restrict__ Wmt, ushort_t* __restrict__ Wgt,
                             ushort_t* __restrict__ Wut) {
    int idx = blockIdx.x * 256 + threadIdx.x;
    if (idx < 65536) {                       // [256][256] -> [n][k]
        int n = idx >> 8, k = idx & 255;
        Wmt[idx] = f2bf(Wm[(size_t)k * 256 + n]);
        Wut[idx] = f2bf(Wu[(size_t)k * 256 + n]);
    }
    if (idx < 131072) {                      // [512][256] -> [n][512 k]
        int n = idx >> 9, k = idx & 511;
        Wgt[idx] = f2bf(Wg[(size_t)k * 256 + n]);
    }
}

__global__ void imap_init(int* __restrict__ imap, int R) {
    int r = blockIdx.x * 256 + threadIdx.x;
    if (r < R) imap[r] = -1;
}
__global__ void imap_scatter(const int* __restrict__ tgt, int* __restrict__ imap, int E) {
    int e = blockIdx.x * 256 + threadIdx.x;
    if (e < E) imap[tgt[e]] = e;
}

// ---------------- x -> bf16 copy ----------------
__global__ void conv_bf16(const float* __restrict__ x, ushort_t* __restrict__ yb, size_t n8) {
    size_t i = (size_t)blockIdx.x * blockDim.x + threadIdx.x;
    size_t stride = (size_t)gridDim.x * blockDim.x;
    for (; i < n8; i += stride)
        *(int4v*)(yb + i * 8) = pack_f32x8_bf16(x + i * 8);
}

// ---------------- segment mean: wave-per-edge, unroll-4 ----------------
__global__ __launch_bounds__(256) void seg_mean_bf16(const ushort_t* __restrict__ yb,
                                                     const int* __restrict__ ptr,
                                                     const int* __restrict__ src,
                                                     ushort_t* __restrict__ smb, int E) {
    int e = blockIdx.x * 4 + (threadIdx.x >> 6);
    if (e >= E) return;
    int lane = threadIdx.x & 63;
    int s = ptr[e], t = ptr[e + 1];
    float a0 = 0.f, a1 = 0.f, a2 = 0.f, a3 = 0.f;
    int i = s;
    for (; i + 4 <= t; i += 4) {
        uint2v v0 = *(const uint2v*)(yb + (size_t)src[i + 0] * H + lane * 4);
        uint2v v1 = *(const uint2v*)(yb + (size_t)src[i + 1] * H + lane * 4);
        uint2v v2 = *(const uint2v*)(yb + (size_t)src[i + 2] * H + lane * 4);
        uint2v v3 = *(const uint2v*)(yb + (size_t)src[i + 3] * H + lane * 4);
        a0 += bf2f(v0.x & 0xffff) + bf2f(v1.x & 0xffff) + bf2f(v2.x & 0xffff) + bf2f(v3.x & 0xffff);
        a1 += bf2f(v0.x >> 16)    + bf2f(v1.x >> 16)    + bf2f(v2.x >> 16)    + bf2f(v3.x >> 16);
        a2 += bf2f(v0.y & 0xffff) + bf2f(v1.y & 0xffff) + bf2f(v2.y & 0xffff) + bf2f(v3.y & 0xffff);
        a3 += bf2f(v0.y >> 16)    + bf2f(v1.y >> 16)    + bf2f(v2.y >> 16)    + bf2f(v3.y >> 16);
    }
    for (; i < t; ++i) {
        uint2v v = *(const uint2v*)(yb + (size_t)src[i] * H + lane * 4);
        a0 += bf2f(v.x & 0xffff); a1 += bf2f(v.x >> 16);
        a2 += bf2f(v.y & 0xffff); a3 += bf2f(v.y >> 16);
    }
    float inv = 1.f / (float)(t - s);
    uint2v o;
    o.x = (unsigned)f2bf(a0 * inv) | ((unsigned)f2bf(a1 * inv) << 16);
    o.y = (unsigned)f2bf(a2 * inv) | ((unsigned)f2bf(a3 * inv) << 16);
    *(uint2v*)(smb + (size_t)e * H + lane * 4) = o;
}

// fallback: fp32 gather (small-ws path)
__global__ __launch_bounds__(256) void seg_mean_f32w(const float* __restrict__ x,
                                                     const int* __restrict__ ptr,
                                                     const int* __restrict__ src,
                                                     ushort_t* __restrict__ smb, int E) {
    int e = blockIdx.x * 4 + (threadIdx.x >> 6);
    if (e >= E) return;
    int lane = threadIdx.x & 63;
    int s = ptr[e], t = ptr[e + 1];
    float a0 = 0.f, a1 = 0.f, a2 = 0.f, a3 = 0.f;
    int i = s;
    for (; i + 4 <= t; i += 4) {
        float4 v0 = *(const float4*)(x + (size_t)src[i + 0] * H + lane * 4);
        float4 v1 = *(const float4*)(x + (size_t)src[i + 1] * H + lane * 4);
        float4 v2 = *(const float4*)(x + (size_t)src[i + 2] * H + lane * 4);
        float4 v3 = *(const float4*)(x + (size_t)src[i + 3] * H + lane * 4);
        a0 += v0.x + v1.x + v2.x + v3.x;
        a1 += v0.y + v1.y + v2.y + v3.y;
        a2 += v0.z + v1.z + v2.z + v3.z;
        a3 += v0.w + v1.w + v2.w + v3.w;
    }
    for (; i < t; ++i) {
        float4 v = *(const float4*)(x + (size_t)src[i] * H + lane * 4);
        a0 += v.x; a1 += v.y; a2 += v.z; a3 += v.w;
    }
    float inv = 1.f / (float)(t - s);
    uint2v o;
    o.x = (unsigned)f2bf(a0 * inv) | ((unsigned)f2bf(a1 * inv) << 16);
    o.y = (unsigned)f2bf(a2 * inv) | ((unsigned)f2bf(a3 * inv) << 16);
    *(uint2v*)(smb + (size_t)e * H + lane * 4) = o;
}

// ---------------- W-resident streaming MFMA GEMM (v2: straight-line) ----------------
// W col-block resident in LDS (128 KiB), swizzled; one barrier; then each wave
// independently streams 16-row A tiles. v2 removes ALL lambdas/array-pointer
// params (rounds 4-5: A tiles were demoted to scratch -> 1.23 GB spill traffic
// per dispatch, VGPR_Count pinned at 128 under both launch_bounds settings).
// Single-buffered A per tile; latency hidden by 8 independent waves/CU.
template<int MODE, int KTOT, int NCOLS, bool XB>
__global__ __launch_bounds__(512, 2) void wgemm(
    const ushort_t* __restrict__ Abf,
    const float* __restrict__ Xf,
    const ushort_t* __restrict__ Xb,
    const ushort_t* __restrict__ Aux,
    const int* __restrict__ Idx,
    const float* __restrict__ Hew,
    const ushort_t* __restrict__ Wt,     // [256][KTOT] bf16 (pre-transposed)
    const float* __restrict__ Bias,
    ushort_t* __restrict__ OutB,
    float* __restrict__ OutF,
    int M)
{
    constexpr int KS  = KTOT / 32;       // K-steps (MFMA K=32 each)
    constexpr int CT  = NCOLS / 16;      // output col-tiles
    constexpr int CPR = KTOT / 8;        // 16B chunks per W row
    const int c0 = blockIdx.y * NCOLS;
    const int tid = threadIdx.x;
    const int wv = tid >> 6;
    const int lane = tid & 63;

    __shared__ __align__(16) ushort_t Ws[NCOLS * KTOT];   // 128 KiB

    // stage W: LDS[n][cs] = W[n][cs ^ (n&7)]  (linear dest, pre-swizzled src)
    {
        constexpr int TOT = NCOLS * CPR;
#pragma unroll 1
        for (int base = wv * 64; base < TOT; base += 512) {
            int id = base + lane;
            int n = id / CPR, cs = id % CPR;
            int cg = cs ^ (n & 7);
            glds16(Wt + (size_t)(c0 + n) * KTOT + cg * 8, (char*)Ws + (size_t)id * 16);
        }
    }
    __syncthreads();   // the only barrier

    const int arow = lane & 15;     // A row within 16-row tile; also W col (mod 16)
    const int kg = lane >> 4;       // k-subgroup (8 elems)

    float biasv[CT];
#pragma unroll
    for (int t = 0; t < CT; ++t) biasv[t] = Bias[c0 + t * 16 + arow];

    const int ntiles = (M + 15) >> 4;
    const int stride = gridDim.x * 8;

    for (int tile = blockIdx.x * 8 + wv; tile < ntiles; tile += stride) {
        int r = tile * 16 + arow; if (r > M - 1) r = M - 1;

        // ---- load A tile (single scope, constant indices only) ----
        short8 A[KS];
        if constexpr (MODE == 0) {
            const ushort_t* p = Abf + (size_t)r * KTOT + kg * 8;
#pragma unroll
            for (int kk = 0; kk < KS; ++kk) A[kk] = *(const short8*)(p + kk * 32);
        } else if constexpr (MODE == 1) {
            int tr = Idx[r];
            if constexpr (XB) {
                const ushort_t* p = Xb + (size_t)tr * 256 + kg * 8;
#pragma unroll
                for (int kk = 0; kk < 8; ++kk) A[kk] = *(const short8*)(p + kk * 32);
            } else {
                const float* p = Xf + (size_t)tr * 256 + kg * 8;
#pragma unroll
                for (int kk = 0; kk < 8; ++kk) { int4v d = pack_f32x8_bf16(p + kk * 32); A[kk] = *(short8*)&d; }
            }
            const ushort_t* q = Aux + (size_t)r * 256 + kg * 8;
#pragma unroll
            for (int kk = 0; kk < 8; ++kk) A[8 + kk] = *(const short8*)(q + kk * 32);
        } else {
            int e = Idx[r];
            if constexpr (XB) {
                const ushort_t* p = (e >= 0) ? (Aux + (size_t)e * 256) : (Xb + (size_t)r * 256);
                p += kg * 8;
#pragma unroll
                for (int kk = 0; kk < KS; ++kk) A[kk] = *(const short8*)(p + kk * 32);
            } else {
                if (e >= 0) {
                    const ushort_t* p = Aux + (size_t)e * 256 + kg * 8;
#pragma unroll
                    for (int kk = 0; kk < KS; ++kk) A[kk] = *(const short8*)(p + kk * 32);
                } else {
                    const float* p = Xf + (size_t)r * 256 + kg * 8;
#pragma unroll
                    for (int kk = 0; kk < KS; ++kk) { int4v d = pack_f32x8_bf16(p + kk * 32); A[kk] = *(short8*)&d; }
                }
            }
        }

        // ---- MFMA against LDS-resident W ----
        f32x4 acc[CT];
#pragma unroll
        for (int t = 0; t < CT; ++t) acc[t] = (f32x4){0.f, 0.f, 0.f, 0.f};
#pragma unroll
        for (int kk = 0; kk < KS; ++kk) {
            int cs = (kg + 4 * kk) ^ (lane & 7);          // W chunk, swizzle-matched
#pragma unroll
            for (int t = 0; t < CT; ++t) {
                int n = arow + 16 * t;
                short8 b = *(const short8*)((const char*)Ws + ((size_t)n * CPR + cs) * 16);
                acc[t] = __builtin_amdgcn_mfma_f32_16x16x32_bf16(A[kk], b, acc[t], 0, 0, 0);
            }
        }

        // ---- epilogue; C/D layout: col = lane&15 (+16t), row = (lane>>4)*4 + i ----
        int rbase = tile * 16 + (lane >> 4) * 4;
        if constexpr (MODE == 0) {
#pragma unroll
            for (int t = 0; t < CT; ++t) {
                int col = c0 + t * 16 + arow;
#pragma unroll
                for (int i = 0; i < 4; ++i) {
                    int rg = rbase + i;
                    if (rg < M) OutB[(size_t)rg * 256 + col] = f2bf(acc[t][i] + biasv[t]);
                }
            }
        } else if constexpr (MODE == 1) {
            int tg0 = Idx[rbase + 0 < M ? rbase + 0 : M - 1];
            int tg1 = Idx[rbase + 1 < M ? rbase + 1 : M - 1];
            int tg2 = Idx[rbase + 2 < M ? rbase + 2 : M - 1];
            int tg3 = Idx[rbase + 3 < M ? rbase + 3 : M - 1];
            float hw0 = Hew[rbase + 0 < M ? rbase + 0 : M - 1];
            float hw1 = Hew[rbase + 1 < M ? rbase + 1 : M - 1];
            float hw2 = Hew[rbase + 2 < M ? rbase + 2 : M - 1];
            float hw3 = Hew[rbase + 3 < M ? rbase + 3 : M - 1];
#pragma unroll
            for (int t = 0; t < CT; ++t) {
                int col = c0 + t * 16 + arow;
                int tg[4] = {tg0, tg1, tg2, tg3};
                float hw[4] = {hw0, hw1, hw2, hw3};
#pragma unroll
                for (int i = 0; i < 4; ++i) {
                    int rg = rbase + i;
                    if (rg < M) {
                        float z = acc[t][i] + biasv[t];
                        float g = 1.f / (1.f + __expf(-z));
                        float tx = XB ? bf2f(Xb[(size_t)tg[i] * 256 + col])
                                      : Xf[(size_t)tg[i] * 256 + col];
                        float m = bf2f(Aux[(size_t)rg * 256 + col]);
                        OutB[(size_t)rg * 256 + col] = f2bf(tx + hw[i] * g * m);
                    }
                }
            }
        } else {
#pragma unroll
            for (int t = 0; t < CT; ++t) {
                int col = c0 + t * 16 + arow;
#pragma unroll
                for (int i = 0; i < 4; ++i) {
                    int rg = rbase + i;
                    if (rg < M) {
                        float z = acc[t][i] + biasv[t];
                        OutF[(size_t)rg * 256 + col] = fminf(fmaxf(z, 0.f), 1.f);
                    }
                }
            }
        }
    }
}

extern "C" void kernel_launch(void* const* d_in, const int* in_sizes, int n_in,
                              void* d_out, int out_size, void* d_ws, size_t ws_size,
                              hipStream_t stream) {
    const float* x      = (const float*)d_in[0];
    const int*   he_ptr = (const int*)d_in[1];
    const int*   he_src = (const int*)d_in[2];
    const int*   he_tgt = (const int*)d_in[3];
    const float* he_w   = (const float*)d_in[4];
    const float* W_msg  = (const float*)d_in[5];
    const float* b_msg  = (const float*)d_in[6];
    const float* W_gate = (const float*)d_in[7];
    const float* b_gate = (const float*)d_in[8];
    const float* W_upd  = (const float*)d_in[9];
    const float* b_upd  = (const float*)d_in[10];

    const int E = in_sizes[3];
    const int R = in_sizes[0] / H;

    const size_t wbytes = (size_t)(65536 + 131072 + 65536) * 2;
    const size_t needA = (size_t)R * H * 2 + (size_t)E * H * 2 * 2 + (size_t)R * 4 + wbytes;
    const bool bigws = ws_size >= needA;

    if (bigws) {
        char* ws = (char*)d_ws;
        ushort_t* yb   = (ushort_t*)ws;                                // R*256 bf16(x)
        ushort_t* buf0 = yb + (size_t)R * H;                           // E*256: smb, later updb
        ushort_t* buf1 = buf0 + (size_t)E * H;                         // E*256: msgb
        int*      imap = (int*)(buf1 + (size_t)E * H);                 // R
        ushort_t* Wmt  = (ushort_t*)((char*)imap + (size_t)R * 4);
        ushort_t* Wgt  = Wmt + 256 * 256;
        ushort_t* Wut  = Wgt + 256 * 512;

        prep_weights<<<512, 256, 0, stream>>>(W_msg, W_gate, W_upd, Wmt, Wgt, Wut);
        imap_init<<<(R + 255) / 256, 256, 0, stream>>>(imap, R);
        imap_scatter<<<(E + 255) / 256, 256, 0, stream>>>(he_tgt, imap, E);
        conv_bf16<<<2048, 256, 0, stream>>>(x, yb, (size_t)R * H / 8);
        seg_mean_bf16<<<(E + 3) / 4, 256, 0, stream>>>(yb, he_ptr, he_src, buf0, E);

        wgemm<0, 256, 256, true><<<dim3(256, 1), 512, 0, stream>>>(
            buf0, nullptr, yb, nullptr, nullptr, nullptr, Wmt, b_msg, buf1, nullptr, E);
        wgemm<1, 512, 128, true><<<dim3(128, 2), 512, 0, stream>>>(
            nullptr, nullptr, yb, buf1, he_tgt, he_w, Wgt, b_gate, buf0, nullptr, E);
        wgemm<2, 256, 256, true><<<dim3(256, 1), 512, 0, stream>>>(
            nullptr, nullptr, yb, buf0, imap, nullptr, Wut, b_upd, nullptr, (float*)d_out, R);
    } else {
        char* ws = (char*)d_ws;
        ushort_t* buf0 = (ushort_t*)ws;
        ushort_t* buf1 = buf0 + (size_t)E * H;
        int*      imap = (int*)(buf1 + (size_t)E * H);
        ushort_t* Wmt  = (ushort_t*)((char*)imap + (size_t)R * 4);
        ushort_t* Wgt  = Wmt + 256 * 256;
        ushort_t* Wut  = Wgt + 256 * 512;

        prep_weights<<<512, 256, 0, stream>>>(W_msg, W_gate, W_upd, Wmt, Wgt, Wut);
        imap_init<<<(R + 255) / 256, 256, 0, stream>>>(imap, R);
        imap_scatter<<<(E + 255) / 256, 256, 0, stream>>>(he_tgt, imap, E);
        seg_mean_f32w<<<(E + 3) / 4, 256, 0, stream>>>(x, he_ptr, he_src, buf0, E);

        wgemm<0, 256, 256, false><<<dim3(256, 1), 512, 0, stream>>>(
            buf0, nullptr, nullptr, nullptr, nullptr, nullptr, Wmt, b_msg, buf1, nullptr, E);
        wgemm<1, 512, 128, false><<<dim3(128, 2), 512, 0, stream>>>(
            nullptr, x, nullptr, buf1, he_tgt, he_w, Wgt, b_gate, buf0, nullptr, E);
        wgemm<2, 256, 256, false><<<dim3(256, 1), 512, 0, stream>>>(
            nullptr, x, nullptr, buf0, imap, nullptr, Wut, b_upd, nullptr, (float*)d_out, R);
    }
}

// Round 7
// 418.549 us; speedup vs baseline: 2.9443x; 2.9443x over previous
//
#include <hip/hip_runtime.h>
#include <math.h>

#define H 256

typedef __attribute__((ext_vector_type(8))) short short8;
typedef __attribute__((ext_vector_type(4))) float f32x4;
typedef __attribute__((ext_vector_type(4))) int int4v;
typedef __attribute__((ext_vector_type(2))) unsigned int uint2v;
typedef unsigned short ushort_t;

__device__ __forceinline__ float bf2f(unsigned short u) {
    union { unsigned int i; float f; } v; v.i = ((unsigned int)u) << 16; return v.f;
}
__device__ __forceinline__ unsigned short f2bf(float f) {
    union { float f; unsigned int i; } v; v.f = f;
    unsigned int r = v.i + 0x7FFFu + ((v.i >> 16) & 1u);   // RNE
    return (unsigned short)(r >> 16);
}
__device__ __forceinline__ void glds16(const void* g, void* l) {
    __builtin_amdgcn_global_load_lds((const __attribute__((address_space(1))) void*)g,
                                     (__attribute__((address_space(3))) void*)l, 16, 0, 0);
}
__device__ __forceinline__ int4v pack_f32x8_bf16(const float* p) {
    float4 f0 = *(const float4*)(p);
    float4 f1 = *(const float4*)(p + 4);
    int4v d;
    d.x = (int)((unsigned)f2bf(f0.x) | ((unsigned)f2bf(f0.y) << 16));
    d.y = (int)((unsigned)f2bf(f0.z) | ((unsigned)f2bf(f0.w) << 16));
    d.z = (int)((unsigned)f2bf(f1.x) | ((unsigned)f2bf(f1.y) << 16));
    d.w = (int)((unsigned)f2bf(f1.z) | ((unsigned)f2bf(f1.w) << 16));
    return d;
}

// ---------------- prep ----------------
__global__ void prep_weights(const float* __restrict__ Wm, const float* __restrict__ Wg,
                             const float* __restrict__ Wu,
                             ushort_t* __restrict__ Wmt, ushort_t* __restrict__ Wgt,
                             ushort_t* __restrict__ Wut) {
    int idx = blockIdx.x * 256 + threadIdx.x;
    if (idx < 65536) {                       // [256][256] -> [n][k]
        int n = idx >> 8, k = idx & 255;
        Wmt[idx] = f2bf(Wm[(size_t)k * 256 + n]);
        Wut[idx] = f2bf(Wu[(size_t)k * 256 + n]);
    }
    if (idx < 131072) {                      // [512][256] -> [n][512 k]
        int n = idx >> 9, k = idx & 511;
        Wgt[idx] = f2bf(Wg[(size_t)k * 256 + n]);
    }
}

__global__ void imap_init(int* __restrict__ imap, int R) {
    int r = blockIdx.x * 256 + threadIdx.x;
    if (r < R) imap[r] = -1;
}
__global__ void imap_scatter(const int* __restrict__ tgt, int* __restrict__ imap, int E) {
    int e = blockIdx.x * 256 + threadIdx.x;
    if (e < E) imap[tgt[e]] = e;
}

// ---------------- x -> bf16 copy ----------------
__global__ void conv_bf16(const float* __restrict__ x, ushort_t* __restrict__ yb, size_t n8) {
    size_t i = (size_t)blockIdx.x * blockDim.x + threadIdx.x;
    size_t stride = (size_t)gridDim.x * blockDim.x;
    for (; i < n8; i += stride)
        *(int4v*)(yb + i * 8) = pack_f32x8_bf16(x + i * 8);
}

// ---------------- segment mean: wave-per-edge, unroll-4 ----------------
__global__ __launch_bounds__(256) void seg_mean_bf16(const ushort_t* __restrict__ yb,
                                                     const int* __restrict__ ptr,
                                                     const int* __restrict__ src,
                                                     ushort_t* __restrict__ smb, int E) {
    int e = blockIdx.x * 4 + (threadIdx.x >> 6);
    if (e >= E) return;
    int lane = threadIdx.x & 63;
    int s = ptr[e], t = ptr[e + 1];
    float a0 = 0.f, a1 = 0.f, a2 = 0.f, a3 = 0.f;
    int i = s;
    for (; i + 4 <= t; i += 4) {
        uint2v v0 = *(const uint2v*)(yb + (size_t)src[i + 0] * H + lane * 4);
        uint2v v1 = *(const uint2v*)(yb + (size_t)src[i + 1] * H + lane * 4);
        uint2v v2 = *(const uint2v*)(yb + (size_t)src[i + 2] * H + lane * 4);
        uint2v v3 = *(const uint2v*)(yb + (size_t)src[i + 3] * H + lane * 4);
        a0 += bf2f(v0.x & 0xffff) + bf2f(v1.x & 0xffff) + bf2f(v2.x & 0xffff) + bf2f(v3.x & 0xffff);
        a1 += bf2f(v0.x >> 16)    + bf2f(v1.x >> 16)    + bf2f(v2.x >> 16)    + bf2f(v3.x >> 16);
        a2 += bf2f(v0.y & 0xffff) + bf2f(v1.y & 0xffff) + bf2f(v2.y & 0xffff) + bf2f(v3.y & 0xffff);
        a3 += bf2f(v0.y >> 16)    + bf2f(v1.y >> 16)    + bf2f(v2.y >> 16)    + bf2f(v3.y >> 16);
    }
    for (; i < t; ++i) {
        uint2v v = *(const uint2v*)(yb + (size_t)src[i] * H + lane * 4);
        a0 += bf2f(v.x & 0xffff); a1 += bf2f(v.x >> 16);
        a2 += bf2f(v.y & 0xffff); a3 += bf2f(v.y >> 16);
    }
    float inv = 1.f / (float)(t - s);
    uint2v o;
    o.x = (unsigned)f2bf(a0 * inv) | ((unsigned)f2bf(a1 * inv) << 16);
    o.y = (unsigned)f2bf(a2 * inv) | ((unsigned)f2bf(a3 * inv) << 16);
    *(uint2v*)(smb + (size_t)e * H + lane * 4) = o;
}

// fallback: fp32 gather (small-ws path)
__global__ __launch_bounds__(256) void seg_mean_f32w(const float* __restrict__ x,
                                                     const int* __restrict__ ptr,
                                                     const int* __restrict__ src,
                                                     ushort_t* __restrict__ smb, int E) {
    int e = blockIdx.x * 4 + (threadIdx.x >> 6);
    if (e >= E) return;
    int lane = threadIdx.x & 63;
    int s = ptr[e], t = ptr[e + 1];
    float a0 = 0.f, a1 = 0.f, a2 = 0.f, a3 = 0.f;
    int i = s;
    for (; i + 4 <= t; i += 4) {
        float4 v0 = *(const float4*)(x + (size_t)src[i + 0] * H + lane * 4);
        float4 v1 = *(const float4*)(x + (size_t)src[i + 1] * H + lane * 4);
        float4 v2 = *(const float4*)(x + (size_t)src[i + 2] * H + lane * 4);
        float4 v3 = *(const float4*)(x + (size_t)src[i + 3] * H + lane * 4);
        a0 += v0.x + v1.x + v2.x + v3.x;
        a1 += v0.y + v1.y + v2.y + v3.y;
        a2 += v0.z + v1.z + v2.z + v3.z;
        a3 += v0.w + v1.w + v2.w + v3.w;
    }
    for (; i < t; ++i) {
        float4 v = *(const float4*)(x + (size_t)src[i] * H + lane * 4);
        a0 += v.x; a1 += v.y; a2 += v.z; a3 += v.w;
    }
    float inv = 1.f / (float)(t - s);
    uint2v o;
    o.x = (unsigned)f2bf(a0 * inv) | ((unsigned)f2bf(a1 * inv) << 16);
    o.y = (unsigned)f2bf(a2 * inv) | ((unsigned)f2bf(a3 * inv) << 16);
    *(uint2v*)(smb + (size_t)e * H + lane * 4) = o;
}

// ---------------- unified MFMA GEMM (round-3 structure, fixed swizzle) ----------------
// C[M,256] = A[M,KTOT] @ W[KTOT,256] (+epilogue). Tile 128x128, BK=32, 4 waves.
// Swizzle fix vs round 3: f(row) = (row>>1)&3 instead of row&3. Old form gave
// only 4 distinct bank slots per 16-row fragment read (4-way conflict, 3.2M
// SQ_LDS_BANK_CONFLICT); new form gives 8 slots -> 2-way, which is free.
template<int MODE, int KTOT, bool XB>
__global__ __launch_bounds__(256) void mfma_gemm(
    const ushort_t* __restrict__ Abf,
    const float* __restrict__ Xf,
    const ushort_t* __restrict__ Xb,
    const ushort_t* __restrict__ Aux,
    const int* __restrict__ Idx,
    const float* __restrict__ Hew,
    const ushort_t* __restrict__ Wt,     // [256][KTOT] bf16 (pre-transposed)
    const float* __restrict__ Bias,      // [256] fp32
    ushort_t* __restrict__ OutB,
    float* __restrict__ OutF,
    int M)
{
    constexpr int NT = KTOT / 32;
    const int m0 = blockIdx.x * 128;
    const int c0 = blockIdx.y * 128;
    const int tid = threadIdx.x;
    const int wv = tid >> 6;
    const int lane = tid & 63;
    const int wr = wv >> 1, wc = wv & 1;

    __shared__ __align__(16) ushort_t As[2][128 * 32];
    __shared__ __align__(16) ushort_t Bs[2][128 * 32];

    f32x4 acc[4][4];
#pragma unroll
    for (int i = 0; i < 4; ++i)
#pragma unroll
        for (int j = 0; j < 4; ++j) acc[i][j] = (f32x4){0.f, 0.f, 0.f, 0.f};

    const int ch0 = wv * 64 + lane;     // LDS chunk id; byte = ch*16
    const int ch1 = ch0 + 256;

    auto stageB = [&](int buf, int k0) {
#pragma unroll
        for (int c = 0; c < 2; ++c) {
            int ch = c ? ch1 : ch0;
            int col = ch >> 2, sl = ch & 3, cc = sl ^ ((col >> 1) & 3);   // XOR swizzle (source side)
            glds16(Wt + (size_t)(c0 + col) * KTOT + (k0 + cc * 8),
                   (char*)(&Bs[buf][0]) + ch * 16);
        }
    };

    auto stageA = [&](int buf, int k0) {
#pragma unroll
        for (int c = 0; c < 2; ++c) {
            int ch = c ? ch1 : ch0;
            int row = ch >> 2, sl = ch & 3, cc = sl ^ ((row >> 1) & 3);
            int kg = k0 + cc * 8;
            int r = m0 + row; if (r > M - 1) r = M - 1;
            if constexpr (MODE == 0) {
                glds16(Abf + (size_t)r * KTOT + kg, (char*)(&As[buf][0]) + ch * 16);
            } else {
                int4v d;
                if constexpr (MODE == 1) {
                    if (k0 < 256) {
                        int tr = Idx[r];
                        if constexpr (XB) d = *(const int4v*)(Xb + (size_t)tr * 256 + kg);
                        else              d = pack_f32x8_bf16(Xf + (size_t)tr * 256 + kg);
                    } else {
                        d = *(const int4v*)(Aux + (size_t)r * 256 + (kg - 256));
                    }
                } else {
                    int e = Idx[r];
                    if (e >= 0) d = *(const int4v*)(Aux + (size_t)e * 256 + kg);
                    else if constexpr (XB) d = *(const int4v*)(Xb + (size_t)r * 256 + kg);
                    else d = pack_f32x8_bf16(Xf + (size_t)r * 256 + kg);
                }
                *(int4v*)((char*)(&As[buf][0]) + ch * 16) = d;
            }
        }
    };

    auto compute = [&](int buf) {
        short8 a[4], b[4];
#pragma unroll
        for (int fm = 0; fm < 4; ++fm) {
            int row = wr * 64 + fm * 16 + (lane & 15);
            int byte = (row * 4 + ((lane >> 4) ^ ((row >> 1) & 3))) * 16;   // XOR swizzle (read side)
            a[fm] = *(const short8*)((const char*)(&As[buf][0]) + byte);
        }
#pragma unroll
        for (int fn = 0; fn < 4; ++fn) {
            int col = wc * 64 + fn * 16 + (lane & 15);
            int byte = (col * 4 + ((lane >> 4) ^ ((col >> 1) & 3))) * 16;
            b[fn] = *(const short8*)((const char*)(&Bs[buf][0]) + byte);
        }
#pragma unroll
        for (int fm = 0; fm < 4; ++fm)
#pragma unroll
            for (int fn = 0; fn < 4; ++fn)
                acc[fm][fn] = __builtin_amdgcn_mfma_f32_16x16x32_bf16(a[fm], b[fn], acc[fm][fn], 0, 0, 0);
    };

    stageA(0, 0); stageB(0, 0);
    __syncthreads();
    for (int kt = 0; kt < NT; ++kt) {
        if (kt + 1 < NT) { stageA((kt + 1) & 1, (kt + 1) * 32); stageB((kt + 1) & 1, (kt + 1) * 32); }
        compute(kt & 1);
        __syncthreads();
    }

    // epilogue: C/D layout col=lane&15, row=(lane>>4)*4+i
#pragma unroll
    for (int fm = 0; fm < 4; ++fm) {
        int rbase = m0 + wr * 64 + fm * 16 + (lane >> 4) * 4;
#pragma unroll
        for (int fn = 0; fn < 4; ++fn) {
            int col = c0 + wc * 64 + fn * 16 + (lane & 15);
            float bia = Bias[col];
            f32x4 v = acc[fm][fn];
#pragma unroll
            for (int i = 0; i < 4; ++i) {
                int rg = rbase + i;
                if (rg < M) {
                    float z = v[i] + bia;
                    if constexpr (MODE == 0) {
                        OutB[(size_t)rg * 256 + col] = f2bf(z);
                    } else if constexpr (MODE == 1) {
                        float g = 1.f / (1.f + __expf(-z));
                        int tr = Idx[rg];
                        float tx;
                        if constexpr (XB) tx = bf2f(Xb[(size_t)tr * 256 + col]);
                        else              tx = Xf[(size_t)tr * 256 + col];
                        float m = bf2f(Aux[(size_t)rg * 256 + col]);
                        float u = tx + Hew[rg] * g * m;
                        OutB[(size_t)rg * 256 + col] = f2bf(u);
                    } else {
                        OutF[(size_t)rg * 256 + col] = fminf(fmaxf(z, 0.f), 1.f);
                    }
                }
            }
        }
    }
}

extern "C" void kernel_launch(void* const* d_in, const int* in_sizes, int n_in,
                              void* d_out, int out_size, void* d_ws, size_t ws_size,
                              hipStream_t stream) {
    const float* x      = (const float*)d_in[0];
    const int*   he_ptr = (const int*)d_in[1];
    const int*   he_src = (const int*)d_in[2];
    const int*   he_tgt = (const int*)d_in[3];
    const float* he_w   = (const float*)d_in[4];
    const float* W_msg  = (const float*)d_in[5];
    const float* b_msg  = (const float*)d_in[6];
    const float* W_gate = (const float*)d_in[7];
    const float* b_gate = (const float*)d_in[8];
    const float* W_upd  = (const float*)d_in[9];
    const float* b_upd  = (const float*)d_in[10];

    const int E = in_sizes[3];
    const int R = in_sizes[0] / H;

    const size_t wbytes = (size_t)(65536 + 131072 + 65536) * 2;
    const size_t needA = (size_t)R * H * 2 + (size_t)E * H * 2 * 2 + (size_t)R * 4 + wbytes;
    const bool bigws = ws_size >= needA;

    dim3 gE((E + 127) / 128, 2);
    dim3 gR((R + 127) / 128, 2);

    if (bigws) {
        char* ws = (char*)d_ws;
        ushort_t* yb   = (ushort_t*)ws;                                // R*256 bf16(x)
        ushort_t* buf0 = yb + (size_t)R * H;                           // E*256: smb, later updb
        ushort_t* buf1 = buf0 + (size_t)E * H;                         // E*256: msgb
        int*      imap = (int*)(buf1 + (size_t)E * H);                 // R
        ushort_t* Wmt  = (ushort_t*)((char*)imap + (size_t)R * 4);
        ushort_t* Wgt  = Wmt + 256 * 256;
        ushort_t* Wut  = Wgt + 256 * 512;

        prep_weights<<<512, 256, 0, stream>>>(W_msg, W_gate, W_upd, Wmt, Wgt, Wut);
        imap_init<<<(R + 255) / 256, 256, 0, stream>>>(imap, R);
        imap_scatter<<<(E + 255) / 256, 256, 0, stream>>>(he_tgt, imap, E);
        conv_bf16<<<2048, 256, 0, stream>>>(x, yb, (size_t)R * H / 8);
        seg_mean_bf16<<<(E + 3) / 4, 256, 0, stream>>>(yb, he_ptr, he_src, buf0, E);

        mfma_gemm<0, 256, true><<<gE, 256, 0, stream>>>(buf0, nullptr, yb, nullptr, nullptr, nullptr,
                                                        Wmt, b_msg, buf1, nullptr, E);
        mfma_gemm<1, 512, true><<<gE, 256, 0, stream>>>(nullptr, nullptr, yb, buf1, he_tgt, he_w,
                                                        Wgt, b_gate, buf0, nullptr, E);
        mfma_gemm<2, 256, true><<<gR, 256, 0, stream>>>(nullptr, nullptr, yb, buf0, imap, nullptr,
                                                        Wut, b_upd, nullptr, (float*)d_out, R);
    } else {
        char* ws = (char*)d_ws;
        ushort_t* buf0 = (ushort_t*)ws;
        ushort_t* buf1 = buf0 + (size_t)E * H;
        int*      imap = (int*)(buf1 + (size_t)E * H);
        ushort_t* Wmt  = (ushort_t*)((char*)imap + (size_t)R * 4);
        ushort_t* Wgt  = Wmt + 256 * 256;
        ushort_t* Wut  = Wgt + 256 * 512;

        prep_weights<<<512, 256, 0, stream>>>(W_msg, W_gate, W_upd, Wmt, Wgt, Wut);
        imap_init<<<(R + 255) / 256, 256, 0, stream>>>(imap, R);
        imap_scatter<<<(E + 255) / 256, 256, 0, stream>>>(he_tgt, imap, E);
        seg_mean_f32w<<<(E + 3) / 4, 256, 0, stream>>>(x, he_ptr, he_src, buf0, E);

        mfma_gemm<0, 256, false><<<gE, 256, 0, stream>>>(buf0, nullptr, nullptr, nullptr, nullptr, nullptr,
                                                         Wmt, b_msg, buf1, nullptr, E);
        mfma_gemm<1, 512, false><<<gE, 256, 0, stream>>>(nullptr, x, nullptr, buf1, he_tgt, he_w,
                                                         Wgt, b_gate, buf0, nullptr, E);
        mfma_gemm<2, 256, false><<<gR, 256, 0, stream>>>(nullptr, x, nullptr, buf0, imap, nullptr,
                                                         Wut, b_upd, nullptr, (float*)d_out, R);
    }
}

// Round 8
// 372.829 us; speedup vs baseline: 3.3054x; 1.1226x over previous
//
#include <hip/hip_runtime.h>
#include <math.h>

#define H 256

typedef __attribute__((ext_vector_type(8))) short short8;
typedef __attribute__((ext_vector_type(4))) float f32x4;
typedef __attribute__((ext_vector_type(4))) int int4v;
typedef __attribute__((ext_vector_type(2))) unsigned int uint2v;
typedef unsigned short ushort_t;

__device__ __forceinline__ float bf2f(unsigned short u) {
    union { unsigned int i; float f; } v; v.i = ((unsigned int)u) << 16; return v.f;
}
__device__ __forceinline__ unsigned short f2bf(float f) {
    union { float f; unsigned int i; } v; v.f = f;
    unsigned int r = v.i + 0x7FFFu + ((v.i >> 16) & 1u);   // RNE
    return (unsigned short)(r >> 16);
}
__device__ __forceinline__ void glds16(const void* g, void* l) {
    __builtin_amdgcn_global_load_lds((const __attribute__((address_space(1))) void*)g,
                                     (__attribute__((address_space(3))) void*)l, 16, 0, 0);
}
__device__ __forceinline__ int4v pack_f32x8_bf16(const float* p) {
    float4 f0 = *(const float4*)(p);
    float4 f1 = *(const float4*)(p + 4);
    int4v d;
    d.x = (int)((unsigned)f2bf(f0.x) | ((unsigned)f2bf(f0.y) << 16));
    d.y = (int)((unsigned)f2bf(f0.z) | ((unsigned)f2bf(f0.w) << 16));
    d.z = (int)((unsigned)f2bf(f1.x) | ((unsigned)f2bf(f1.y) << 16));
    d.w = (int)((unsigned)f2bf(f1.z) | ((unsigned)f2bf(f1.w) << 16));
    return d;
}

// ---------------- prep ----------------
__global__ void prep_weights(const float* __restrict__ Wm, const float* __restrict__ Wg,
                             const float* __restrict__ Wu,
                             ushort_t* __restrict__ Wmt, ushort_t* __restrict__ Wgt,
                             ushort_t* __restrict__ Wut) {
    int idx = blockIdx.x * 256 + threadIdx.x;
    if (idx < 65536) {                       // [256][256] -> [n][k]
        int n = idx >> 8, k = idx & 255;
        Wmt[idx] = f2bf(Wm[(size_t)k * 256 + n]);
        Wut[idx] = f2bf(Wu[(size_t)k * 256 + n]);
    }
    if (idx < 131072) {                      // [512][256] -> [n][512 k]
        int n = idx >> 9, k = idx & 511;
        Wgt[idx] = f2bf(Wg[(size_t)k * 256 + n]);
    }
}

__global__ void imap_init(int* __restrict__ imap, int R) {
    int r = blockIdx.x * 256 + threadIdx.x;
    if (r < R) imap[r] = -1;
}
__global__ void imap_scatter(const int* __restrict__ tgt, int* __restrict__ imap, int E) {
    int e = blockIdx.x * 256 + threadIdx.x;
    if (e < E) imap[tgt[e]] = e;
}

// ---------------- x -> bf16 copy ----------------
__global__ void conv_bf16(const float* __restrict__ x, ushort_t* __restrict__ yb, size_t n8) {
    size_t i = (size_t)blockIdx.x * blockDim.x + threadIdx.x;
    size_t stride = (size_t)gridDim.x * blockDim.x;
    for (; i < n8; i += stride)
        *(int4v*)(yb + i * 8) = pack_f32x8_bf16(x + i * 8);
}

// ---------------- segment mean: wave-per-edge, unroll-4 ----------------
__global__ __launch_bounds__(256) void seg_mean_bf16(const ushort_t* __restrict__ yb,
                                                     const int* __restrict__ ptr,
                                                     const int* __restrict__ src,
                                                     ushort_t* __restrict__ smb, int E) {
    int e = blockIdx.x * 4 + (threadIdx.x >> 6);
    if (e >= E) return;
    int lane = threadIdx.x & 63;
    int s = ptr[e], t = ptr[e + 1];
    float a0 = 0.f, a1 = 0.f, a2 = 0.f, a3 = 0.f;
    int i = s;
    for (; i + 4 <= t; i += 4) {
        uint2v v0 = *(const uint2v*)(yb + (size_t)src[i + 0] * H + lane * 4);
        uint2v v1 = *(const uint2v*)(yb + (size_t)src[i + 1] * H + lane * 4);
        uint2v v2 = *(const uint2v*)(yb + (size_t)src[i + 2] * H + lane * 4);
        uint2v v3 = *(const uint2v*)(yb + (size_t)src[i + 3] * H + lane * 4);
        a0 += bf2f(v0.x & 0xffff) + bf2f(v1.x & 0xffff) + bf2f(v2.x & 0xffff) + bf2f(v3.x & 0xffff);
        a1 += bf2f(v0.x >> 16)    + bf2f(v1.x >> 16)    + bf2f(v2.x >> 16)    + bf2f(v3.x >> 16);
        a2 += bf2f(v0.y & 0xffff) + bf2f(v1.y & 0xffff) + bf2f(v2.y & 0xffff) + bf2f(v3.y & 0xffff);
        a3 += bf2f(v0.y >> 16)    + bf2f(v1.y >> 16)    + bf2f(v2.y >> 16)    + bf2f(v3.y >> 16);
    }
    for (; i < t; ++i) {
        uint2v v = *(const uint2v*)(yb + (size_t)src[i] * H + lane * 4);
        a0 += bf2f(v.x & 0xffff); a1 += bf2f(v.x >> 16);
        a2 += bf2f(v.y & 0xffff); a3 += bf2f(v.y >> 16);
    }
    float inv = 1.f / (float)(t - s);
    uint2v o;
    o.x = (unsigned)f2bf(a0 * inv) | ((unsigned)f2bf(a1 * inv) << 16);
    o.y = (unsigned)f2bf(a2 * inv) | ((unsigned)f2bf(a3 * inv) << 16);
    *(uint2v*)(smb + (size_t)e * H + lane * 4) = o;
}

// fallback: fp32 gather (small-ws path)
__global__ __launch_bounds__(256) void seg_mean_f32w(const float* __restrict__ x,
                                                     const int* __restrict__ ptr,
                                                     const int* __restrict__ src,
                                                     ushort_t* __restrict__ smb, int E) {
    int e = blockIdx.x * 4 + (threadIdx.x >> 6);
    if (e >= E) return;
    int lane = threadIdx.x & 63;
    int s = ptr[e], t = ptr[e + 1];
    float a0 = 0.f, a1 = 0.f, a2 = 0.f, a3 = 0.f;
    int i = s;
    for (; i + 4 <= t; i += 4) {
        float4 v0 = *(const float4*)(x + (size_t)src[i + 0] * H + lane * 4);
        float4 v1 = *(const float4*)(x + (size_t)src[i + 1] * H + lane * 4);
        float4 v2 = *(const float4*)(x + (size_t)src[i + 2] * H + lane * 4);
        float4 v3 = *(const float4*)(x + (size_t)src[i + 3] * H + lane * 4);
        a0 += v0.x + v1.x + v2.x + v3.x;
        a1 += v0.y + v1.y + v2.y + v3.y;
        a2 += v0.z + v1.z + v2.z + v3.z;
        a3 += v0.w + v1.w + v2.w + v3.w;
    }
    for (; i < t; ++i) {
        float4 v = *(const float4*)(x + (size_t)src[i] * H + lane * 4);
        a0 += v.x; a1 += v.y; a2 += v.z; a3 += v.w;
    }
    float inv = 1.f / (float)(t - s);
    uint2v o;
    o.x = (unsigned)f2bf(a0 * inv) | ((unsigned)f2bf(a1 * inv) << 16);
    o.y = (unsigned)f2bf(a2 * inv) | ((unsigned)f2bf(a3 * inv) << 16);
    *(uint2v*)(smb + (size_t)e * H + lane * 4) = o;
}

// helper macro: load one 16B A-chunk for K-offset k0v into int4v variable `d`
// (textual inline -> no lambda/param demotion; rounds 4-6 lesson)
#define LOADA_CHUNK(k0v, d)                                                              \
    do {                                                                                 \
        if constexpr (MODE == 1) {                                                       \
            if ((k0v) < 256) {                                                           \
                if constexpr (XB) d = *(const int4v*)(pX + (k0v));                       \
                else              d = pack_f32x8_bf16(pXf + (k0v));                      \
            } else {                                                                     \
                d = *(const int4v*)(pA + ((k0v) - 256));                                 \
            }                                                                            \
        } else {                                                                         \
            if constexpr (XB) d = *(const int4v*)(p2 + (k0v));                           \
            else { if (!useF) d = *(const int4v*)(p2 + (k0v));                           \
                   else       d = pack_f32x8_bf16(p2f + (k0v)); }                        \
        }                                                                                \
    } while (0)

// ---------------- full-N MFMA GEMM (8 waves, 128x256 tile, T14 K-loop) ----------------
// C[M,256] = A[M,KTOT] @ W[KTOT,256] (+epilogue). One barrier per K-step:
//   sync -> issue stage(kt+1) (loads only) -> compute(kt) -> ds_write A(kt+1)
// Gather latency hides under the 16 MFMAs; no grid.y => A fetched once.
// MODE 0: A = Abf rows (glds16).       Epi: OutB = bf16(z + bias).
// MODE 1: A row e = [x[tgt[e]] | Aux[e]] (KTOT=512, reg-staged).
//         Epi: g=sigmoid(z+bias); OutB = bf16(tx + hew*g*m).
// MODE 2: A row r = Idx[r]>=0 ? Aux[Idx[r]] : x[r] (reg-staged).
//         Epi: OutF = clip(z+bias,0,1) fp32.
template<int MODE, int KTOT, bool XB>
__global__ __launch_bounds__(512, 4) void wgemm(
    const ushort_t* __restrict__ Abf,
    const float* __restrict__ Xf,
    const ushort_t* __restrict__ Xb,
    const ushort_t* __restrict__ Aux,
    const int* __restrict__ Idx,
    const float* __restrict__ Hew,
    const ushort_t* __restrict__ Wt,     // [256][KTOT] bf16 (pre-transposed)
    const float* __restrict__ Bias,      // [256] fp32
    ushort_t* __restrict__ OutB,
    float* __restrict__ OutF,
    int M)
{
    constexpr int NT = KTOT / 32;
    const int m0 = blockIdx.x * 128;
    const int tid = threadIdx.x;
    const int wv = tid >> 6;
    const int lane = tid & 63;
    const int wr = wv >> 2, wc = wv & 3;    // waves 2 (rows) x 4 (cols)

    __shared__ __align__(16) ushort_t As[2][128 * 32];   // 16 KiB
    __shared__ __align__(16) ushort_t Bs[2][256 * 32];   // 32 KiB

    // ---- staging geometry (swizzle verified conflict-free in round 7) ----
    const int aRow  = tid >> 2;             // 0..127
    const int sl    = tid & 3;
    const int aCc   = sl ^ ((aRow >> 1) & 3);
    const int bCol0 = tid >> 2;             // 0..127
    const int bCol1 = bCol0 + 128;          // 128..255
    const int bCc0  = sl ^ ((bCol0 >> 1) & 3);
    const int bCc1  = sl ^ ((bCol1 >> 1) & 3);

    const ushort_t* bSrc0 = Wt + (size_t)bCol0 * KTOT + bCc0 * 8;
    const ushort_t* bSrc1 = Wt + (size_t)bCol1 * KTOT + bCc1 * 8;

    int r = m0 + aRow; if (r > M - 1) r = M - 1;

    const ushort_t* aSrc = nullptr;
    const ushort_t* pX = nullptr;  const float* pXf = nullptr;
    const ushort_t* pA = nullptr;
    const ushort_t* p2 = nullptr;  const float* p2f = nullptr;
    bool useF = false;
    if constexpr (MODE == 0) {
        aSrc = Abf + (size_t)r * KTOT + aCc * 8;
    } else if constexpr (MODE == 1) {
        int tr = Idx[r];
        if constexpr (XB) pX = Xb + (size_t)tr * 256 + aCc * 8;
        else              pXf = Xf + (size_t)tr * 256 + aCc * 8;
        pA = Aux + (size_t)r * 256 + aCc * 8;
    } else {
        int e = Idx[r];
        if constexpr (XB) {
            p2 = (e >= 0 ? Aux + (size_t)e * 256 : Xb + (size_t)r * 256) + aCc * 8;
        } else {
            if (e >= 0) { p2 = Aux + (size_t)e * 256 + aCc * 8; useF = false; }
            else        { p2f = Xf + (size_t)r * 256 + aCc * 8; useF = true; }
        }
    }

    f32x4 acc[4][4];
#pragma unroll
    for (int i = 0; i < 4; ++i)
#pragma unroll
        for (int j = 0; j < 4; ++j) acc[i][j] = (f32x4){0.f, 0.f, 0.f, 0.f};

    // ---- prologue: stage tile 0 ----
    glds16(bSrc0, (char*)&Bs[0][0] + tid * 16);
    glds16(bSrc1, (char*)&Bs[0][0] + (tid + 512) * 16);
    if constexpr (MODE == 0) {
        glds16(aSrc, (char*)&As[0][0] + tid * 16);
    } else {
        int4v d0; LOADA_CHUNK(0, d0);
        *(int4v*)((char*)&As[0][0] + tid * 16) = d0;
    }

    // ---- K loop: one barrier per step ----
#pragma unroll 2
    for (int kt = 0; kt < NT; ++kt) {
        __syncthreads();                      // drains stage(kt): issued one compute-phase ago
        const int cur = kt & 1;
        const int nxt = cur ^ 1;
        const bool more = (kt + 1 < NT);
        int4v pf;
        if (more) {
            const int k0 = (kt + 1) * 32;
            glds16(bSrc0 + k0, (char*)&Bs[nxt][0] + tid * 16);
            glds16(bSrc1 + k0, (char*)&Bs[nxt][0] + (tid + 512) * 16);
            if constexpr (MODE == 0) {
                glds16(aSrc + k0, (char*)&As[nxt][0] + tid * 16);
            } else {
                LOADA_CHUNK(k0, pf);          // issue only; wait lands after MFMAs
            }
        }

        // fragments: row/col local, swizzle-matched reads (2-way = free)
        const char* aBase = (const char*)&As[cur][0];
        const char* bBase = (const char*)&Bs[cur][0];
        const int kg = lane >> 4;
        short8 a0, a1, a2, a3;
        {
            int r0 = wr * 64 + 0 * 16 + (lane & 15);
            int r1 = r0 + 16, r2 = r0 + 32, r3 = r0 + 48;
            a0 = *(const short8*)(aBase + (r0 * 4 + (kg ^ ((r0 >> 1) & 3))) * 16);
            a1 = *(const short8*)(aBase + (r1 * 4 + (kg ^ ((r1 >> 1) & 3))) * 16);
            a2 = *(const short8*)(aBase + (r2 * 4 + (kg ^ ((r2 >> 1) & 3))) * 16);
            a3 = *(const short8*)(aBase + (r3 * 4 + (kg ^ ((r3 >> 1) & 3))) * 16);
        }
#pragma unroll
        for (int fn = 0; fn < 4; ++fn) {
            int cn = wc * 64 + fn * 16 + (lane & 15);
            short8 b = *(const short8*)(bBase + (cn * 4 + (kg ^ ((cn >> 1) & 3))) * 16);
            acc[0][fn] = __builtin_amdgcn_mfma_f32_16x16x32_bf16(a0, b, acc[0][fn], 0, 0, 0);
            acc[1][fn] = __builtin_amdgcn_mfma_f32_16x16x32_bf16(a1, b, acc[1][fn], 0, 0, 0);
            acc[2][fn] = __builtin_amdgcn_mfma_f32_16x16x32_bf16(a2, b, acc[2][fn], 0, 0, 0);
            acc[3][fn] = __builtin_amdgcn_mfma_f32_16x16x32_bf16(a3, b, acc[3][fn], 0, 0, 0);
        }
        if (more) {
            if constexpr (MODE != 0) {
                *(int4v*)((char*)&As[nxt][0] + tid * 16) = pf;   // vmcnt wait covered by MFMAs
            }
        }
    }

    // ---- epilogue: C/D layout col=lane&15, row=(lane>>4)*4+i ----
#pragma unroll
    for (int fm = 0; fm < 4; ++fm) {
        int rbase = m0 + wr * 64 + fm * 16 + (lane >> 4) * 4;
#pragma unroll
        for (int fn = 0; fn < 4; ++fn) {
            int col = wc * 64 + fn * 16 + (lane & 15);
            float bia = Bias[col];
            f32x4 v = acc[fm][fn];
#pragma unroll
            for (int i = 0; i < 4; ++i) {
                int rg = rbase + i;
                if (rg < M) {
                    float z = v[i] + bia;
                    if constexpr (MODE == 0) {
                        OutB[(size_t)rg * 256 + col] = f2bf(z);
                    } else if constexpr (MODE == 1) {
                        float g = 1.f / (1.f + __expf(-z));
                        int tr = Idx[rg];
                        float tx;
                        if constexpr (XB) tx = bf2f(Xb[(size_t)tr * 256 + col]);
                        else              tx = Xf[(size_t)tr * 256 + col];
                        float m = bf2f(Aux[(size_t)rg * 256 + col]);
                        float u = tx + Hew[rg] * g * m;
                        OutB[(size_t)rg * 256 + col] = f2bf(u);
                    } else {
                        OutF[(size_t)rg * 256 + col] = fminf(fmaxf(z, 0.f), 1.f);
                    }
                }
            }
        }
    }
}

extern "C" void kernel_launch(void* const* d_in, const int* in_sizes, int n_in,
                              void* d_out, int out_size, void* d_ws, size_t ws_size,
                              hipStream_t stream) {
    const float* x      = (const float*)d_in[0];
    const int*   he_ptr = (const int*)d_in[1];
    const int*   he_src = (const int*)d_in[2];
    const int*   he_tgt = (const int*)d_in[3];
    const float* he_w   = (const float*)d_in[4];
    const float* W_msg  = (const float*)d_in[5];
    const float* b_msg  = (const float*)d_in[6];
    const float* W_gate = (const float*)d_in[7];
    const float* b_gate = (const float*)d_in[8];
    const float* W_upd  = (const float*)d_in[9];
    const float* b_upd  = (const float*)d_in[10];

    const int E = in_sizes[3];
    const int R = in_sizes[0] / H;

    const size_t wbytes = (size_t)(65536 + 131072 + 65536) * 2;
    const size_t needA = (size_t)R * H * 2 + (size_t)E * H * 2 * 2 + (size_t)R * 4 + wbytes;
    const bool bigws = ws_size >= needA;

    const int gE = (E + 127) / 128;
    const int gR = (R + 127) / 128;

    if (bigws) {
        char* ws = (char*)d_ws;
        ushort_t* yb   = (ushort_t*)ws;                                // R*256 bf16(x)
        ushort_t* buf0 = yb + (size_t)R * H;                           // E*256: smb, later updb
        ushort_t* buf1 = buf0 + (size_t)E * H;                         // E*256: msgb
        int*      imap = (int*)(buf1 + (size_t)E * H);                 // R
        ushort_t* Wmt  = (ushort_t*)((char*)imap + (size_t)R * 4);
        ushort_t* Wgt  = Wmt + 256 * 256;
        ushort_t* Wut  = Wgt + 256 * 512;

        prep_weights<<<512, 256, 0, stream>>>(W_msg, W_gate, W_upd, Wmt, Wgt, Wut);
        imap_init<<<(R + 255) / 256, 256, 0, stream>>>(imap, R);
        imap_scatter<<<(E + 255) / 256, 256, 0, stream>>>(he_tgt, imap, E);
        conv_bf16<<<2048, 256, 0, stream>>>(x, yb, (size_t)R * H / 8);
        seg_mean_bf16<<<(E + 3) / 4, 256, 0, stream>>>(yb, he_ptr, he_src, buf0, E);

        wgemm<0, 256, true><<<gE, 512, 0, stream>>>(buf0, nullptr, yb, nullptr, nullptr, nullptr,
                                                    Wmt, b_msg, buf1, nullptr, E);
        wgemm<1, 512, true><<<gE, 512, 0, stream>>>(nullptr, nullptr, yb, buf1, he_tgt, he_w,
                                                    Wgt, b_gate, buf0, nullptr, E);
        wgemm<2, 256, true><<<gR, 512, 0, stream>>>(nullptr, nullptr, yb, buf0, imap, nullptr,
                                                    Wut, b_upd, nullptr, (float*)d_out, R);
    } else {
        char* ws = (char*)d_ws;
        ushort_t* buf0 = (ushort_t*)ws;
        ushort_t* buf1 = buf0 + (size_t)E * H;
        int*      imap = (int*)(buf1 + (size_t)E * H);
        ushort_t* Wmt  = (ushort_t*)((char*)imap + (size_t)R * 4);
        ushort_t* Wgt  = Wmt + 256 * 256;
        ushort_t* Wut  = Wgt + 256 * 512;

        prep_weights<<<512, 256, 0, stream>>>(W_msg, W_gate, W_upd, Wmt, Wgt, Wut);
        imap_init<<<(R + 255) / 256, 256, 0, stream>>>(imap, R);
        imap_scatter<<<(E + 255) / 256, 256, 0, stream>>>(he_tgt, imap, E);
        seg_mean_f32w<<<(E + 3) / 4, 256, 0, stream>>>(x, he_ptr, he_src, buf0, E);

        wgemm<0, 256, false><<<gE, 512, 0, stream>>>(buf0, nullptr, nullptr, nullptr, nullptr, nullptr,
                                                     Wmt, b_msg, buf1, nullptr, E);
        wgemm<1, 512, false><<<gE, 512, 0, stream>>>(nullptr, x, nullptr, buf1, he_tgt, he_w,
                                                     Wgt, b_gate, buf0, nullptr, E);
        wgemm<2, 256, false><<<gR, 512, 0, stream>>>(nullptr, x, nullptr, buf0, imap, nullptr,
                                                     Wut, b_upd, nullptr, (float*)d_out, R);
    }
}

// Round 9
// 369.893 us; speedup vs baseline: 3.3316x; 1.0079x over previous
//
#include <hip/hip_runtime.h>
#include <math.h>

#define H 256

typedef __attribute__((ext_vector_type(8))) short short8;
typedef __attribute__((ext_vector_type(4))) float f32x4;
typedef __attribute__((ext_vector_type(4))) int int4v;
typedef __attribute__((ext_vector_type(2))) unsigned int uint2v;
typedef unsigned short ushort_t;

__device__ __forceinline__ float bf2f(unsigned short u) {
    union { unsigned int i; float f; } v; v.i = ((unsigned int)u) << 16; return v.f;
}
__device__ __forceinline__ unsigned short f2bf(float f) {
    union { float f; unsigned int i; } v; v.f = f;
    unsigned int r = v.i + 0x7FFFu + ((v.i >> 16) & 1u);   // RNE
    return (unsigned short)(r >> 16);
}
__device__ __forceinline__ void glds16(const void* g, void* l) {
    __builtin_amdgcn_global_load_lds((const __attribute__((address_space(1))) void*)g,
                                     (__attribute__((address_space(3))) void*)l, 16, 0, 0);
}
__device__ __forceinline__ int4v pack_f32x8_bf16(const float* p) {
    float4 f0 = *(const float4*)(p);
    float4 f1 = *(const float4*)(p + 4);
    int4v d;
    d.x = (int)((unsigned)f2bf(f0.x) | ((unsigned)f2bf(f0.y) << 16));
    d.y = (int)((unsigned)f2bf(f0.z) | ((unsigned)f2bf(f0.w) << 16));
    d.z = (int)((unsigned)f2bf(f1.x) | ((unsigned)f2bf(f1.y) << 16));
    d.w = (int)((unsigned)f2bf(f1.z) | ((unsigned)f2bf(f1.w) << 16));
    return d;
}

// ---------------- fused prep: weights transpose+cast, imap init, x->bf16 ----------------
__global__ void prep_all(const float* __restrict__ Wm, const float* __restrict__ Wg,
                         const float* __restrict__ Wu, const float* __restrict__ x,
                         ushort_t* __restrict__ Wmt, ushort_t* __restrict__ Wgt,
                         ushort_t* __restrict__ Wut, int* __restrict__ imap,
                         ushort_t* __restrict__ yb, int R, size_t n8) {
    size_t gtid = (size_t)blockIdx.x * blockDim.x + threadIdx.x;
    size_t stride = (size_t)gridDim.x * blockDim.x;
    for (size_t i = gtid; i < 65536; i += stride) {
        int n = (int)(i >> 8), k = (int)(i & 255);
        Wmt[i] = f2bf(Wm[(size_t)k * 256 + n]);
        Wut[i] = f2bf(Wu[(size_t)k * 256 + n]);
    }
    for (size_t i = gtid; i < 131072; i += stride) {
        int n = (int)(i >> 9), k = (int)(i & 511);
        Wgt[i] = f2bf(Wg[(size_t)k * 256 + n]);
    }
    for (size_t i = gtid; i < (size_t)R; i += stride) imap[i] = -1;
    for (size_t i = gtid; i < n8; i += stride)
        *(int4v*)(yb + i * 8) = pack_f32x8_bf16(x + i * 8);
}

__global__ void imap_scatter(const int* __restrict__ tgt, int* __restrict__ imap, int E) {
    int e = blockIdx.x * 256 + threadIdx.x;
    if (e < E) imap[tgt[e]] = e;
}

// ---------------- segment mean: wave-per-edge, unroll-8/4 ----------------
__global__ __launch_bounds__(256) void seg_mean_bf16(const ushort_t* __restrict__ yb,
                                                     const int* __restrict__ ptr,
                                                     const int* __restrict__ src,
                                                     ushort_t* __restrict__ smb, int E) {
    int e = blockIdx.x * 4 + (threadIdx.x >> 6);
    if (e >= E) return;
    int lane = threadIdx.x & 63;
    int s = ptr[e], t = ptr[e + 1];
    float a0 = 0.f, a1 = 0.f, a2 = 0.f, a3 = 0.f;
    int i = s;
    for (; i + 8 <= t; i += 8) {
        uint2v v0 = *(const uint2v*)(yb + (size_t)src[i + 0] * H + lane * 4);
        uint2v v1 = *(const uint2v*)(yb + (size_t)src[i + 1] * H + lane * 4);
        uint2v v2 = *(const uint2v*)(yb + (size_t)src[i + 2] * H + lane * 4);
        uint2v v3 = *(const uint2v*)(yb + (size_t)src[i + 3] * H + lane * 4);
        uint2v v4 = *(const uint2v*)(yb + (size_t)src[i + 4] * H + lane * 4);
        uint2v v5 = *(const uint2v*)(yb + (size_t)src[i + 5] * H + lane * 4);
        uint2v v6 = *(const uint2v*)(yb + (size_t)src[i + 6] * H + lane * 4);
        uint2v v7 = *(const uint2v*)(yb + (size_t)src[i + 7] * H + lane * 4);
        a0 += bf2f(v0.x & 0xffff) + bf2f(v1.x & 0xffff) + bf2f(v2.x & 0xffff) + bf2f(v3.x & 0xffff)
            + bf2f(v4.x & 0xffff) + bf2f(v5.x & 0xffff) + bf2f(v6.x & 0xffff) + bf2f(v7.x & 0xffff);
        a1 += bf2f(v0.x >> 16) + bf2f(v1.x >> 16) + bf2f(v2.x >> 16) + bf2f(v3.x >> 16)
            + bf2f(v4.x >> 16) + bf2f(v5.x >> 16) + bf2f(v6.x >> 16) + bf2f(v7.x >> 16);
        a2 += bf2f(v0.y & 0xffff) + bf2f(v1.y & 0xffff) + bf2f(v2.y & 0xffff) + bf2f(v3.y & 0xffff)
            + bf2f(v4.y & 0xffff) + bf2f(v5.y & 0xffff) + bf2f(v6.y & 0xffff) + bf2f(v7.y & 0xffff);
        a3 += bf2f(v0.y >> 16) + bf2f(v1.y >> 16) + bf2f(v2.y >> 16) + bf2f(v3.y >> 16)
            + bf2f(v4.y >> 16) + bf2f(v5.y >> 16) + bf2f(v6.y >> 16) + bf2f(v7.y >> 16);
    }
    for (; i + 4 <= t; i += 4) {
        uint2v v0 = *(const uint2v*)(yb + (size_t)src[i + 0] * H + lane * 4);
        uint2v v1 = *(const uint2v*)(yb + (size_t)src[i + 1] * H + lane * 4);
        uint2v v2 = *(const uint2v*)(yb + (size_t)src[i + 2] * H + lane * 4);
        uint2v v3 = *(const uint2v*)(yb + (size_t)src[i + 3] * H + lane * 4);
        a0 += bf2f(v0.x & 0xffff) + bf2f(v1.x & 0xffff) + bf2f(v2.x & 0xffff) + bf2f(v3.x & 0xffff);
        a1 += bf2f(v0.x >> 16)    + bf2f(v1.x >> 16)    + bf2f(v2.x >> 16)    + bf2f(v3.x >> 16);
        a2 += bf2f(v0.y & 0xffff) + bf2f(v1.y & 0xffff) + bf2f(v2.y & 0xffff) + bf2f(v3.y & 0xffff);
        a3 += bf2f(v0.y >> 16)    + bf2f(v1.y >> 16)    + bf2f(v2.y >> 16)    + bf2f(v3.y >> 16);
    }
    for (; i < t; ++i) {
        uint2v v = *(const uint2v*)(yb + (size_t)src[i] * H + lane * 4);
        a0 += bf2f(v.x & 0xffff); a1 += bf2f(v.x >> 16);
        a2 += bf2f(v.y & 0xffff); a3 += bf2f(v.y >> 16);
    }
    float inv = 1.f / (float)(t - s);
    uint2v o;
    o.x = (unsigned)f2bf(a0 * inv) | ((unsigned)f2bf(a1 * inv) << 16);
    o.y = (unsigned)f2bf(a2 * inv) | ((unsigned)f2bf(a3 * inv) << 16);
    *(uint2v*)(smb + (size_t)e * H + lane * 4) = o;
}

// fallback: fp32 gather (small-ws path)
__global__ __launch_bounds__(256) void seg_mean_f32w(const float* __restrict__ x,
                                                     const int* __restrict__ ptr,
                                                     const int* __restrict__ src,
                                                     ushort_t* __restrict__ smb, int E) {
    int e = blockIdx.x * 4 + (threadIdx.x >> 6);
    if (e >= E) return;
    int lane = threadIdx.x & 63;
    int s = ptr[e], t = ptr[e + 1];
    float a0 = 0.f, a1 = 0.f, a2 = 0.f, a3 = 0.f;
    int i = s;
    for (; i + 4 <= t; i += 4) {
        float4 v0 = *(const float4*)(x + (size_t)src[i + 0] * H + lane * 4);
        float4 v1 = *(const float4*)(x + (size_t)src[i + 1] * H + lane * 4);
        float4 v2 = *(const float4*)(x + (size_t)src[i + 2] * H + lane * 4);
        float4 v3 = *(const float4*)(x + (size_t)src[i + 3] * H + lane * 4);
        a0 += v0.x + v1.x + v2.x + v3.x;
        a1 += v0.y + v1.y + v2.y + v3.y;
        a2 += v0.z + v1.z + v2.z + v3.z;
        a3 += v0.w + v1.w + v2.w + v3.w;
    }
    for (; i < t; ++i) {
        float4 v = *(const float4*)(x + (size_t)src[i] * H + lane * 4);
        a0 += v.x; a1 += v.y; a2 += v.z; a3 += v.w;
    }
    float inv = 1.f / (float)(t - s);
    uint2v o;
    o.x = (unsigned)f2bf(a0 * inv) | ((unsigned)f2bf(a1 * inv) << 16);
    o.y = (unsigned)f2bf(a2 * inv) | ((unsigned)f2bf(a3 * inv) << 16);
    *(uint2v*)(smb + (size_t)e * H + lane * 4) = o;
}

// reg-stage chunk loader for the fp32 fallback path only
#define LOADA_CHUNK_F(k0v, d)                                                            \
    do {                                                                                 \
        if constexpr (MODE == 1) {                                                       \
            if ((k0v) < 256) d = pack_f32x8_bf16(pXf + (k0v));                           \
            else             d = *(const int4v*)(pA + ((k0v) - 256));                    \
        } else {                                                                         \
            if (!useF) d = *(const int4v*)(p2 + (k0v));                                  \
            else       d = pack_f32x8_bf16(p2f + (k0v));                                 \
        }                                                                                \
    } while (0)

// ---------------- full-N MFMA GEMM (8 waves, 128x256 tile, T14 K-loop) ----------------
// All A-staging via global_load_lds with PER-LANE global addresses (valid: only
// the LDS dest must be wave-uniform-base + lane*16, which tid*16 satisfies).
// One barrier per K-step: sync -> issue stage(kt+1) -> compute(kt).
template<int MODE, int KTOT, bool XB>
__global__ __launch_bounds__(512, 4) void wgemm(
    const ushort_t* __restrict__ Abf,
    const float* __restrict__ Xf,
    const ushort_t* __restrict__ Xb,
    const ushort_t* __restrict__ Aux,
    const int* __restrict__ Idx,
    const float* __restrict__ Hew,
    const ushort_t* __restrict__ Wt,     // [256][KTOT] bf16 (pre-transposed)
    const float* __restrict__ Bias,      // [256] fp32
    ushort_t* __restrict__ OutB,
    float* __restrict__ OutF,
    int M)
{
    constexpr int NT = KTOT / 32;
    const int m0 = blockIdx.x * 128;
    const int tid = threadIdx.x;
    const int wv = tid >> 6;
    const int lane = tid & 63;
    const int wr = wv >> 2, wc = wv & 3;    // waves 2 (rows) x 4 (cols)

    __shared__ __align__(16) ushort_t As[2][128 * 32];   // 16 KiB
    __shared__ __align__(16) ushort_t Bs[2][256 * 32];   // 32 KiB

    // ---- staging geometry (swizzle verified conflict-free in round 7) ----
    const int aRow  = tid >> 2;             // 0..127
    const int sl    = tid & 3;
    const int aCc   = sl ^ ((aRow >> 1) & 3);
    const int bCol0 = tid >> 2;
    const int bCol1 = bCol0 + 128;
    const int bCc0  = sl ^ ((bCol0 >> 1) & 3);
    const int bCc1  = sl ^ ((bCol1 >> 1) & 3);

    const ushort_t* bSrc0 = Wt + (size_t)bCol0 * KTOT + bCc0 * 8;
    const ushort_t* bSrc1 = Wt + (size_t)bCol1 * KTOT + bCc1 * 8;

    int r = m0 + aRow; if (r > M - 1) r = M - 1;

    // per-lane A source pointers
    const ushort_t* aP0 = nullptr;          // k domain [0,256)
    const ushort_t* aP1 = nullptr;          // k domain [256,512) (MODE1 only)
    const float* pXf = nullptr; const ushort_t* pA = nullptr;   // fp32 fallback
    const ushort_t* p2 = nullptr; const float* p2f = nullptr;
    bool useF = false;
    if constexpr (MODE == 0) {
        aP0 = Abf + (size_t)r * KTOT + aCc * 8;
    } else if constexpr (MODE == 1) {
        int tr = Idx[r];
        if constexpr (XB) {
            aP0 = Xb + (size_t)tr * 256 + aCc * 8;
            aP1 = Aux + (size_t)r * 256 + aCc * 8 - 256;   // +k0 with k0>=256 lands right
        } else {
            pXf = Xf + (size_t)tr * 256 + aCc * 8;
            pA  = Aux + (size_t)r * 256 + aCc * 8;
        }
    } else {
        int e = Idx[r];
        if constexpr (XB) {
            aP0 = (e >= 0 ? Aux + (size_t)e * 256 : Xb + (size_t)r * 256) + aCc * 8;
        } else {
            if (e >= 0) { p2 = Aux + (size_t)e * 256 + aCc * 8; useF = false; }
            else        { p2f = Xf + (size_t)r * 256 + aCc * 8; useF = true; }
        }
    }

    f32x4 acc[4][4];
#pragma unroll
    for (int i = 0; i < 4; ++i)
#pragma unroll
        for (int j = 0; j < 4; ++j) acc[i][j] = (f32x4){0.f, 0.f, 0.f, 0.f};

    // ---- prologue: stage tile 0 ----
    glds16(bSrc0, (char*)&Bs[0][0] + tid * 16);
    glds16(bSrc1, (char*)&Bs[0][0] + (tid + 512) * 16);
    if constexpr (MODE == 0 || XB) {
        glds16(aP0, (char*)&As[0][0] + tid * 16);
    } else {
        int4v d0; LOADA_CHUNK_F(0, d0);
        *(int4v*)((char*)&As[0][0] + tid * 16) = d0;
    }

    // ---- K loop: one barrier per step ----
#pragma unroll 2
    for (int kt = 0; kt < NT; ++kt) {
        __syncthreads();                      // drains stage(kt): issued one compute-phase ago
        const int cur = kt & 1;
        const int nxt = cur ^ 1;
        const bool more = (kt + 1 < NT);
        int4v pf;
        if (more) {
            const int k0 = (kt + 1) * 32;
            glds16(bSrc0 + k0, (char*)&Bs[nxt][0] + tid * 16);
            glds16(bSrc1 + k0, (char*)&Bs[nxt][0] + (tid + 512) * 16);
            if constexpr (MODE == 0) {
                glds16(aP0 + k0, (char*)&As[nxt][0] + tid * 16);
            } else if constexpr (XB) {
                if constexpr (MODE == 1) {
                    const ushort_t* s = (k0 < 256) ? (aP0 + k0) : (aP1 + k0);
                    glds16(s, (char*)&As[nxt][0] + tid * 16);
                } else {
                    glds16(aP0 + k0, (char*)&As[nxt][0] + tid * 16);
                }
            } else {
                LOADA_CHUNK_F(k0, pf);        // issue only; wait lands after MFMAs
            }
        }

        // fragments: swizzle-matched reads (2-way = free)
        const char* aBase = (const char*)&As[cur][0];
        const char* bBase = (const char*)&Bs[cur][0];
        const int kg = lane >> 4;
        short8 a0, a1, a2, a3;
        {
            int r0 = wr * 64 + 0 * 16 + (lane & 15);
            int r1 = r0 + 16, r2 = r0 + 32, r3 = r0 + 48;
            a0 = *(const short8*)(aBase + (r0 * 4 + (kg ^ ((r0 >> 1) & 3))) * 16);
            a1 = *(const short8*)(aBase + (r1 * 4 + (kg ^ ((r1 >> 1) & 3))) * 16);
            a2 = *(const short8*)(aBase + (r2 * 4 + (kg ^ ((r2 >> 1) & 3))) * 16);
            a3 = *(const short8*)(aBase + (r3 * 4 + (kg ^ ((r3 >> 1) & 3))) * 16);
        }
#pragma unroll
        for (int fn = 0; fn < 4; ++fn) {
            int cn = wc * 64 + fn * 16 + (lane & 15);
            short8 b = *(const short8*)(bBase + (cn * 4 + (kg ^ ((cn >> 1) & 3))) * 16);
            acc[0][fn] = __builtin_amdgcn_mfma_f32_16x16x32_bf16(a0, b, acc[0][fn], 0, 0, 0);
            acc[1][fn] = __builtin_amdgcn_mfma_f32_16x16x32_bf16(a1, b, acc[1][fn], 0, 0, 0);
            acc[2][fn] = __builtin_amdgcn_mfma_f32_16x16x32_bf16(a2, b, acc[2][fn], 0, 0, 0);
            acc[3][fn] = __builtin_amdgcn_mfma_f32_16x16x32_bf16(a3, b, acc[3][fn], 0, 0, 0);
        }
        if (more) {
            if constexpr (MODE != 0 && !XB) {
                *(int4v*)((char*)&As[nxt][0] + tid * 16) = pf;   // vmcnt wait covered by MFMAs
            }
        }
    }

    // ---- epilogue: C/D layout col=lane&15, row=(lane>>4)*4+i ----
#pragma unroll
    for (int fm = 0; fm < 4; ++fm) {
        int rbase = m0 + wr * 64 + fm * 16 + (lane >> 4) * 4;
#pragma unroll
        for (int fn = 0; fn < 4; ++fn) {
            int col = wc * 64 + fn * 16 + (lane & 15);
            float bia = Bias[col];
            f32x4 v = acc[fm][fn];
#pragma unroll
            for (int i = 0; i < 4; ++i) {
                int rg = rbase + i;
                if (rg < M) {
                    float z = v[i] + bia;
                    if constexpr (MODE == 0) {
                        OutB[(size_t)rg * 256 + col] = f2bf(z);
                    } else if constexpr (MODE == 1) {
                        float g = 1.f / (1.f + __expf(-z));
                        int tr = Idx[rg];
                        float tx;
                        if constexpr (XB) tx = bf2f(Xb[(size_t)tr * 256 + col]);
                        else              tx = Xf[(size_t)tr * 256 + col];
                        float m = bf2f(Aux[(size_t)rg * 256 + col]);
                        float u = tx + Hew[rg] * g * m;
                        OutB[(size_t)rg * 256 + col] = f2bf(u);
                    } else {
                        OutF[(size_t)rg * 256 + col] = fminf(fmaxf(z, 0.f), 1.f);
                    }
                }
            }
        }
    }
}

extern "C" void kernel_launch(void* const* d_in, const int* in_sizes, int n_in,
                              void* d_out, int out_size, void* d_ws, size_t ws_size,
                              hipStream_t stream) {
    const float* x      = (const float*)d_in[0];
    const int*   he_ptr = (const int*)d_in[1];
    const int*   he_src = (const int*)d_in[2];
    const int*   he_tgt = (const int*)d_in[3];
    const float* he_w   = (const float*)d_in[4];
    const float* W_msg  = (const float*)d_in[5];
    const float* b_msg  = (const float*)d_in[6];
    const float* W_gate = (const float*)d_in[7];
    const float* b_gate = (const float*)d_in[8];
    const float* W_upd  = (const float*)d_in[9];
    const float* b_upd  = (const float*)d_in[10];

    const int E = in_sizes[3];
    const int R = in_sizes[0] / H;

    const size_t wbytes = (size_t)(65536 + 131072 + 65536) * 2;
    const size_t needA = (size_t)R * H * 2 + (size_t)E * H * 2 * 2 + (size_t)R * 4 + wbytes;
    const bool bigws = ws_size >= needA;

    const int gE = (E + 127) / 128;
    const int gR = (R + 127) / 128;

    if (bigws) {
        char* ws = (char*)d_ws;
        ushort_t* yb   = (ushort_t*)ws;                                // R*256 bf16(x)
        ushort_t* buf0 = yb + (size_t)R * H;                           // E*256: smb, later updb
        ushort_t* buf1 = buf0 + (size_t)E * H;                         // E*256: msgb
        int*      imap = (int*)(buf1 + (size_t)E * H);                 // R
        ushort_t* Wmt  = (ushort_t*)((char*)imap + (size_t)R * 4);
        ushort_t* Wgt  = Wmt + 256 * 256;
        ushort_t* Wut  = Wgt + 256 * 512;

        prep_all<<<2048, 256, 0, stream>>>(W_msg, W_gate, W_upd, x,
                                           Wmt, Wgt, Wut, imap, yb, R, (size_t)R * H / 8);
        imap_scatter<<<(E + 255) / 256, 256, 0, stream>>>(he_tgt, imap, E);
        seg_mean_bf16<<<(E + 3) / 4, 256, 0, stream>>>(yb, he_ptr, he_src, buf0, E);

        wgemm<0, 256, true><<<gE, 512, 0, stream>>>(buf0, nullptr, yb, nullptr, nullptr, nullptr,
                                                    Wmt, b_msg, buf1, nullptr, E);
        wgemm<1, 512, true><<<gE, 512, 0, stream>>>(nullptr, nullptr, yb, buf1, he_tgt, he_w,
                                                    Wgt, b_gate, buf0, nullptr, E);
        wgemm<2, 256, true><<<gR, 512, 0, stream>>>(nullptr, nullptr, yb, buf0, imap, nullptr,
                                                    Wut, b_upd, nullptr, (float*)d_out, R);
    } else {
        char* ws = (char*)d_ws;
        ushort_t* buf0 = (ushort_t*)ws;
        ushort_t* buf1 = buf0 + (size_t)E * H;
        int*      imap = (int*)(buf1 + (size_t)E * H);
        ushort_t* Wmt  = (ushort_t*)((char*)imap + (size_t)R * 4);
        ushort_t* Wgt  = Wmt + 256 * 256;
        ushort_t* Wut  = Wgt + 256 * 512;

        prep_all<<<2048, 256, 0, stream>>>(W_msg, W_gate, W_upd, x,
                                           Wmt, Wgt, Wut, imap, (ushort_t*)nullptr, R, 0);
        imap_scatter<<<(E + 255) / 256, 256, 0, stream>>>(he_tgt, imap, E);
        seg_mean_f32w<<<(E + 3) / 4, 256, 0, stream>>>(x, he_ptr, he_src, buf0, E);

        wgemm<0, 256, false><<<gE, 512, 0, stream>>>(buf0, nullptr, nullptr, nullptr, nullptr, nullptr,
                                                     Wmt, b_msg, buf1, nullptr, E);
        wgemm<1, 512, false><<<gE, 512, 0, stream>>>(nullptr, x, nullptr, buf1, he_tgt, he_w,
                                                     Wgt, b_gate, buf0, nullptr, E);
        wgemm<2, 256, false><<<gR, 512, 0, stream>>>(nullptr, x, nullptr, buf0, imap, nullptr,
                                                     Wut, b_upd, nullptr, (float*)d_out, R);
    }
}

// Round 10
// 357.333 us; speedup vs baseline: 3.4487x; 1.0352x over previous
//
#include <hip/hip_runtime.h>
#include <math.h>

#define H 256

typedef __attribute__((ext_vector_type(8))) short short8;
typedef __attribute__((ext_vector_type(4))) float f32x4;
typedef __attribute__((ext_vector_type(4))) int int4v;
typedef __attribute__((ext_vector_type(2))) unsigned int uint2v;
typedef unsigned short ushort_t;

__device__ __forceinline__ float bf2f(unsigned short u) {
    union { unsigned int i; float f; } v; v.i = ((unsigned int)u) << 16; return v.f;
}
__device__ __forceinline__ unsigned short f2bf(float f) {
    union { float f; unsigned int i; } v; v.f = f;
    unsigned int r = v.i + 0x7FFFu + ((v.i >> 16) & 1u);   // RNE
    return (unsigned short)(r >> 16);
}
__device__ __forceinline__ void glds16(const void* g, void* l) {
    __builtin_amdgcn_global_load_lds((const __attribute__((address_space(1))) void*)g,
                                     (__attribute__((address_space(3))) void*)l, 16, 0, 0);
}
__device__ __forceinline__ int4v pack_f32x8_bf16(const float* p) {
    float4 f0 = *(const float4*)(p);
    float4 f1 = *(const float4*)(p + 4);
    int4v d;
    d.x = (int)((unsigned)f2bf(f0.x) | ((unsigned)f2bf(f0.y) << 16));
    d.y = (int)((unsigned)f2bf(f0.z) | ((unsigned)f2bf(f0.w) << 16));
    d.z = (int)((unsigned)f2bf(f1.x) | ((unsigned)f2bf(f1.y) << 16));
    d.w = (int)((unsigned)f2bf(f1.z) | ((unsigned)f2bf(f1.w) << 16));
    return d;
}

// ---------------- fused prep: weights transpose+cast, (opt) imap init, x->bf16 ----------------
__global__ void prep_all(const float* __restrict__ Wm, const float* __restrict__ Wg,
                         const float* __restrict__ Wu, const float* __restrict__ x,
                         ushort_t* __restrict__ Wmt, ushort_t* __restrict__ Wgt,
                         ushort_t* __restrict__ Wut, int* __restrict__ imap,
                         ushort_t* __restrict__ yb, int R, size_t n8) {
    size_t gtid = (size_t)blockIdx.x * blockDim.x + threadIdx.x;
    size_t stride = (size_t)gridDim.x * blockDim.x;
    for (size_t i = gtid; i < 65536; i += stride) {
        int n = (int)(i >> 8), k = (int)(i & 255);
        Wmt[i] = f2bf(Wm[(size_t)k * 256 + n]);
        Wut[i] = f2bf(Wu[(size_t)k * 256 + n]);
    }
    for (size_t i = gtid; i < 131072; i += stride) {
        int n = (int)(i >> 9), k = (int)(i & 511);
        Wgt[i] = f2bf(Wg[(size_t)k * 256 + n]);
    }
    if (imap) for (size_t i = gtid; i < (size_t)R; i += stride) imap[i] = -1;
    if (yb) for (size_t i = gtid; i < n8; i += stride)
        *(int4v*)(yb + i * 8) = pack_f32x8_bf16(x + i * 8);
}

__global__ void imap_scatter(const int* __restrict__ tgt, int* __restrict__ imap, int E) {
    int e = blockIdx.x * 256 + threadIdx.x;
    if (e < E) imap[tgt[e]] = e;
}

// ---------------- segment mean: wave-per-edge, unroll-8/4 ----------------
__global__ __launch_bounds__(256) void seg_mean_bf16(const ushort_t* __restrict__ yb,
                                                     const int* __restrict__ ptr,
                                                     const int* __restrict__ src,
                                                     ushort_t* __restrict__ smb, int E) {
    int e = blockIdx.x * 4 + (threadIdx.x >> 6);
    if (e >= E) return;
    int lane = threadIdx.x & 63;
    int s = ptr[e], t = ptr[e + 1];
    float a0 = 0.f, a1 = 0.f, a2 = 0.f, a3 = 0.f;
    int i = s;
    for (; i + 8 <= t; i += 8) {
        uint2v v0 = *(const uint2v*)(yb + (size_t)src[i + 0] * H + lane * 4);
        uint2v v1 = *(const uint2v*)(yb + (size_t)src[i + 1] * H + lane * 4);
        uint2v v2 = *(const uint2v*)(yb + (size_t)src[i + 2] * H + lane * 4);
        uint2v v3 = *(const uint2v*)(yb + (size_t)src[i + 3] * H + lane * 4);
        uint2v v4 = *(const uint2v*)(yb + (size_t)src[i + 4] * H + lane * 4);
        uint2v v5 = *(const uint2v*)(yb + (size_t)src[i + 5] * H + lane * 4);
        uint2v v6 = *(const uint2v*)(yb + (size_t)src[i + 6] * H + lane * 4);
        uint2v v7 = *(const uint2v*)(yb + (size_t)src[i + 7] * H + lane * 4);
        a0 += bf2f(v0.x & 0xffff) + bf2f(v1.x & 0xffff) + bf2f(v2.x & 0xffff) + bf2f(v3.x & 0xffff)
            + bf2f(v4.x & 0xffff) + bf2f(v5.x & 0xffff) + bf2f(v6.x & 0xffff) + bf2f(v7.x & 0xffff);
        a1 += bf2f(v0.x >> 16) + bf2f(v1.x >> 16) + bf2f(v2.x >> 16) + bf2f(v3.x >> 16)
            + bf2f(v4.x >> 16) + bf2f(v5.x >> 16) + bf2f(v6.x >> 16) + bf2f(v7.x >> 16);
        a2 += bf2f(v0.y & 0xffff) + bf2f(v1.y & 0xffff) + bf2f(v2.y & 0xffff) + bf2f(v3.y & 0xffff)
            + bf2f(v4.y & 0xffff) + bf2f(v5.y & 0xffff) + bf2f(v6.y & 0xffff) + bf2f(v7.y & 0xffff);
        a3 += bf2f(v0.y >> 16) + bf2f(v1.y >> 16) + bf2f(v2.y >> 16) + bf2f(v3.y >> 16)
            + bf2f(v4.y >> 16) + bf2f(v5.y >> 16) + bf2f(v6.y >> 16) + bf2f(v7.y >> 16);
    }
    for (; i + 4 <= t; i += 4) {
        uint2v v0 = *(const uint2v*)(yb + (size_t)src[i + 0] * H + lane * 4);
        uint2v v1 = *(const uint2v*)(yb + (size_t)src[i + 1] * H + lane * 4);
        uint2v v2 = *(const uint2v*)(yb + (size_t)src[i + 2] * H + lane * 4);
        uint2v v3 = *(const uint2v*)(yb + (size_t)src[i + 3] * H + lane * 4);
        a0 += bf2f(v0.x & 0xffff) + bf2f(v1.x & 0xffff) + bf2f(v2.x & 0xffff) + bf2f(v3.x & 0xffff);
        a1 += bf2f(v0.x >> 16)    + bf2f(v1.x >> 16)    + bf2f(v2.x >> 16)    + bf2f(v3.x >> 16);
        a2 += bf2f(v0.y & 0xffff) + bf2f(v1.y & 0xffff) + bf2f(v2.y & 0xffff) + bf2f(v3.y & 0xffff);
        a3 += bf2f(v0.y >> 16)    + bf2f(v1.y >> 16)    + bf2f(v2.y >> 16)    + bf2f(v3.y >> 16);
    }
    for (; i < t; ++i) {
        uint2v v = *(const uint2v*)(yb + (size_t)src[i] * H + lane * 4);
        a0 += bf2f(v.x & 0xffff); a1 += bf2f(v.x >> 16);
        a2 += bf2f(v.y & 0xffff); a3 += bf2f(v.y >> 16);
    }
    float inv = 1.f / (float)(t - s);
    uint2v o;
    o.x = (unsigned)f2bf(a0 * inv) | ((unsigned)f2bf(a1 * inv) << 16);
    o.y = (unsigned)f2bf(a2 * inv) | ((unsigned)f2bf(a3 * inv) << 16);
    *(uint2v*)(smb + (size_t)e * H + lane * 4) = o;
}

// fallback: fp32 gather (small-ws path)
__global__ __launch_bounds__(256) void seg_mean_f32w(const float* __restrict__ x,
                                                     const int* __restrict__ ptr,
                                                     const int* __restrict__ src,
                                                     ushort_t* __restrict__ smb, int E) {
    int e = blockIdx.x * 4 + (threadIdx.x >> 6);
    if (e >= E) return;
    int lane = threadIdx.x & 63;
    int s = ptr[e], t = ptr[e + 1];
    float a0 = 0.f, a1 = 0.f, a2 = 0.f, a3 = 0.f;
    int i = s;
    for (; i + 4 <= t; i += 4) {
        float4 v0 = *(const float4*)(x + (size_t)src[i + 0] * H + lane * 4);
        float4 v1 = *(const float4*)(x + (size_t)src[i + 1] * H + lane * 4);
        float4 v2 = *(const float4*)(x + (size_t)src[i + 2] * H + lane * 4);
        float4 v3 = *(const float4*)(x + (size_t)src[i + 3] * H + lane * 4);
        a0 += v0.x + v1.x + v2.x + v3.x;
        a1 += v0.y + v1.y + v2.y + v3.y;
        a2 += v0.z + v1.z + v2.z + v3.z;
        a3 += v0.w + v1.w + v2.w + v3.w;
    }
    for (; i < t; ++i) {
        float4 v = *(const float4*)(x + (size_t)src[i] * H + lane * 4);
        a0 += v.x; a1 += v.y; a2 += v.z; a3 += v.w;
    }
    float inv = 1.f / (float)(t - s);
    uint2v o;
    o.x = (unsigned)f2bf(a0 * inv) | ((unsigned)f2bf(a1 * inv) << 16);
    o.y = (unsigned)f2bf(a2 * inv) | ((unsigned)f2bf(a3 * inv) << 16);
    *(uint2v*)(smb + (size_t)e * H + lane * 4) = o;
}

// reg-stage chunk loader for the fp32 fallback path only
#define LOADA_CHUNK_F(k0v, d)                                                            \
    do {                                                                                 \
        if constexpr (MODE == 1) {                                                       \
            if ((k0v) < 256) d = pack_f32x8_bf16(pXf + (k0v));                           \
            else             d = *(const int4v*)(pA + ((k0v) - 256));                    \
        } else {                                                                         \
            if (!useF) d = *(const int4v*)(p2 + (k0v));                                  \
            else       d = pack_f32x8_bf16(p2f + (k0v));                                 \
        }                                                                                \
    } while (0)

// ---------------- full-N MFMA GEMM (8 waves, 128x256 tile, T14 K-loop) ----------------
// MODE 0: A = Abf rows (glds16 linear).  Epi: OutB = bf16(z + bias).
// MODE 1: A row e = [x[tgt[e]] | Aux[e]] (KTOT=512).
//         Epi: g=sigmoid(z+bias); u = tx + hew*g*m.
//         XB=true: scatter u into OutB[tgt[e]] (tgt injective, tiles partition e
//                  -> no cross-block row aliasing; rows are 512B-aligned).
//         XB=false: OutB[e] (fallback).
// MODE 2: fallback imap path: A row r = Idx[r]>=0 ? Aux[Idx[r]] : x[r]; fp32 clip.
// MODE 3: A = Abf rows (glds16 linear).  Epi: OutF = clip(z+bias,0,1) fp32.
template<int MODE, int KTOT, bool XB>
__global__ __launch_bounds__(512, 4) void wgemm(
    const ushort_t* __restrict__ Abf,
    const float* __restrict__ Xf,
    const ushort_t* __restrict__ Xb,
    const ushort_t* __restrict__ Aux,
    const int* __restrict__ Idx,
    const float* __restrict__ Hew,
    const ushort_t* __restrict__ Wt,     // [256][KTOT] bf16 (pre-transposed)
    const float* __restrict__ Bias,      // [256] fp32
    ushort_t* __restrict__ OutB,
    float* __restrict__ OutF,
    int M)
{
    constexpr int NT = KTOT / 32;
    const int m0 = blockIdx.x * 128;
    const int tid = threadIdx.x;
    const int wv = tid >> 6;
    const int lane = tid & 63;
    const int wr = wv >> 2, wc = wv & 3;    // waves 2 (rows) x 4 (cols)

    __shared__ __align__(16) ushort_t As[2][128 * 32];   // 16 KiB
    __shared__ __align__(16) ushort_t Bs[2][256 * 32];   // 32 KiB

    // ---- staging geometry (swizzle verified conflict-free in round 7) ----
    const int aRow  = tid >> 2;             // 0..127
    const int sl    = tid & 3;
    const int aCc   = sl ^ ((aRow >> 1) & 3);
    const int bCol0 = tid >> 2;
    const int bCol1 = bCol0 + 128;
    const int bCc0  = sl ^ ((bCol0 >> 1) & 3);
    const int bCc1  = sl ^ ((bCol1 >> 1) & 3);

    const ushort_t* bSrc0 = Wt + (size_t)bCol0 * KTOT + bCc0 * 8;
    const ushort_t* bSrc1 = Wt + (size_t)bCol1 * KTOT + bCc1 * 8;

    int r = m0 + aRow; if (r > M - 1) r = M - 1;

    // per-lane A source pointers
    const ushort_t* aP0 = nullptr;          // k domain [0,256)
    const ushort_t* aP1 = nullptr;          // k domain [256,512) (MODE1 only)
    const float* pXf = nullptr; const ushort_t* pA = nullptr;   // fp32 fallback
    const ushort_t* p2 = nullptr; const float* p2f = nullptr;
    bool useF = false;
    if constexpr (MODE == 0 || MODE == 3) {
        aP0 = Abf + (size_t)r * KTOT + aCc * 8;
    } else if constexpr (MODE == 1) {
        int tr = Idx[r];
        if constexpr (XB) {
            aP0 = Xb + (size_t)tr * 256 + aCc * 8;
            aP1 = Aux + (size_t)r * 256 + aCc * 8 - 256;   // +k0 with k0>=256 lands right
        } else {
            pXf = Xf + (size_t)tr * 256 + aCc * 8;
            pA  = Aux + (size_t)r * 256 + aCc * 8;
        }
    } else {
        int e = Idx[r];
        if (e >= 0) { p2 = Aux + (size_t)e * 256 + aCc * 8; useF = false; }
        else        { p2f = Xf + (size_t)r * 256 + aCc * 8; useF = true; }
    }

    f32x4 acc[4][4];
#pragma unroll
    for (int i = 0; i < 4; ++i)
#pragma unroll
        for (int j = 0; j < 4; ++j) acc[i][j] = (f32x4){0.f, 0.f, 0.f, 0.f};

    // ---- prologue: stage tile 0 ----
    glds16(bSrc0, (char*)&Bs[0][0] + tid * 16);
    glds16(bSrc1, (char*)&Bs[0][0] + (tid + 512) * 16);
    if constexpr (MODE == 0 || MODE == 3 || (MODE == 1 && XB)) {
        glds16(aP0, (char*)&As[0][0] + tid * 16);
    } else {
        int4v d0; LOADA_CHUNK_F(0, d0);
        *(int4v*)((char*)&As[0][0] + tid * 16) = d0;
    }

    // ---- K loop: one barrier per step ----
#pragma unroll 2
    for (int kt = 0; kt < NT; ++kt) {
        __syncthreads();                      // drains stage(kt): issued one compute-phase ago
        const int cur = kt & 1;
        const int nxt = cur ^ 1;
        const bool more = (kt + 1 < NT);
        int4v pf;
        if (more) {
            const int k0 = (kt + 1) * 32;
            glds16(bSrc0 + k0, (char*)&Bs[nxt][0] + tid * 16);
            glds16(bSrc1 + k0, (char*)&Bs[nxt][0] + (tid + 512) * 16);
            if constexpr (MODE == 0 || MODE == 3) {
                glds16(aP0 + k0, (char*)&As[nxt][0] + tid * 16);
            } else if constexpr (MODE == 1 && XB) {
                const ushort_t* s = (k0 < 256) ? (aP0 + k0) : (aP1 + k0);
                glds16(s, (char*)&As[nxt][0] + tid * 16);
            } else {
                LOADA_CHUNK_F(k0, pf);        // issue only; wait lands after MFMAs
            }
        }

        // fragments: swizzle-matched reads (2-way = free)
        const char* aBase = (const char*)&As[cur][0];
        const char* bBase = (const char*)&Bs[cur][0];
        const int kg = lane >> 4;
        short8 a0, a1, a2, a3;
        {
            int r0 = wr * 64 + 0 * 16 + (lane & 15);
            int r1 = r0 + 16, r2 = r0 + 32, r3 = r0 + 48;
            a0 = *(const short8*)(aBase + (r0 * 4 + (kg ^ ((r0 >> 1) & 3))) * 16);
            a1 = *(const short8*)(aBase + (r1 * 4 + (kg ^ ((r1 >> 1) & 3))) * 16);
            a2 = *(const short8*)(aBase + (r2 * 4 + (kg ^ ((r2 >> 1) & 3))) * 16);
            a3 = *(const short8*)(aBase + (r3 * 4 + (kg ^ ((r3 >> 1) & 3))) * 16);
        }
#pragma unroll
        for (int fn = 0; fn < 4; ++fn) {
            int cn = wc * 64 + fn * 16 + (lane & 15);
            short8 b = *(const short8*)(bBase + (cn * 4 + (kg ^ ((cn >> 1) & 3))) * 16);
            acc[0][fn] = __builtin_amdgcn_mfma_f32_16x16x32_bf16(a0, b, acc[0][fn], 0, 0, 0);
            acc[1][fn] = __builtin_amdgcn_mfma_f32_16x16x32_bf16(a1, b, acc[1][fn], 0, 0, 0);
            acc[2][fn] = __builtin_amdgcn_mfma_f32_16x16x32_bf16(a2, b, acc[2][fn], 0, 0, 0);
            acc[3][fn] = __builtin_amdgcn_mfma_f32_16x16x32_bf16(a3, b, acc[3][fn], 0, 0, 0);
        }
        if (more) {
            if constexpr (MODE == 2 || (MODE == 1 && !XB)) {
                *(int4v*)((char*)&As[nxt][0] + tid * 16) = pf;   // vmcnt wait covered by MFMAs
            }
        }
    }

    // ---- epilogue: C/D layout col=lane&15, row=(lane>>4)*4+i ----
#pragma unroll
    for (int fm = 0; fm < 4; ++fm) {
        int rbase = m0 + wr * 64 + fm * 16 + (lane >> 4) * 4;
#pragma unroll
        for (int fn = 0; fn < 4; ++fn) {
            int col = wc * 64 + fn * 16 + (lane & 15);
            float bia = Bias[col];
            f32x4 v = acc[fm][fn];
#pragma unroll
            for (int i = 0; i < 4; ++i) {
                int rg = rbase + i;
                if (rg < M) {
                    float z = v[i] + bia;
                    if constexpr (MODE == 0) {
                        OutB[(size_t)rg * 256 + col] = f2bf(z);
                    } else if constexpr (MODE == 1) {
                        float g = 1.f / (1.f + __expf(-z));
                        int tr = Idx[rg];
                        float tx;
                        if constexpr (XB) tx = bf2f(Xb[(size_t)tr * 256 + col]);
                        else              tx = Xf[(size_t)tr * 256 + col];
                        float m = bf2f(Aux[(size_t)rg * 256 + col]);
                        float u = tx + Hew[rg] * g * m;
                        if constexpr (XB) OutB[(size_t)tr * 256 + col] = f2bf(u);   // scatter into yb
                        else              OutB[(size_t)rg * 256 + col] = f2bf(u);
                    } else {
                        OutF[(size_t)rg * 256 + col] = fminf(fmaxf(z, 0.f), 1.f);
                    }
                }
            }
        }
    }
}

extern "C" void kernel_launch(void* const* d_in, const int* in_sizes, int n_in,
                              void* d_out, int out_size, void* d_ws, size_t ws_size,
                              hipStream_t stream) {
    const float* x      = (const float*)d_in[0];
    const int*   he_ptr = (const int*)d_in[1];
    const int*   he_src = (const int*)d_in[2];
    const int*   he_tgt = (const int*)d_in[3];
    const float* he_w   = (const float*)d_in[4];
    const float* W_msg  = (const float*)d_in[5];
    const float* b_msg  = (const float*)d_in[6];
    const float* W_gate = (const float*)d_in[7];
    const float* b_gate = (const float*)d_in[8];
    const float* W_upd  = (const float*)d_in[9];
    const float* b_upd  = (const float*)d_in[10];

    const int E = in_sizes[3];
    const int R = in_sizes[0] / H;

    const size_t wbytes = (size_t)(65536 + 131072 + 65536) * 2;
    const size_t needA = (size_t)R * H * 2 + (size_t)E * H * 2 * 2 + (size_t)R * 4 + wbytes;
    const bool bigws = ws_size >= needA;

    const int gE = (E + 127) / 128;
    const int gR = (R + 127) / 128;

    if (bigws) {
        char* ws = (char*)d_ws;
        ushort_t* yb   = (ushort_t*)ws;                                // R*256 bf16(x); becomes y after gemm2
        ushort_t* buf0 = yb + (size_t)R * H;                           // E*256: smb
        ushort_t* buf1 = buf0 + (size_t)E * H;                         // E*256: msgb
        ushort_t* Wmt  = (ushort_t*)(buf1 + (size_t)E * H);
        ushort_t* Wgt  = Wmt + 256 * 256;
        ushort_t* Wut  = Wgt + 256 * 512;

        prep_all<<<2048, 256, 0, stream>>>(W_msg, W_gate, W_upd, x,
                                           Wmt, Wgt, Wut, (int*)nullptr, yb, R, (size_t)R * H / 8);
        seg_mean_bf16<<<(E + 3) / 4, 256, 0, stream>>>(yb, he_ptr, he_src, buf0, E);

        // msg = smb @ Wm + b          (buf0 -> buf1)
        wgemm<0, 256, true><<<gE, 512, 0, stream>>>(buf0, nullptr, yb, nullptr, nullptr, nullptr,
                                                    Wmt, b_msg, buf1, nullptr, E);
        // gate + gated residual; u scattered into yb[tgt[e]]  -> yb becomes y
        wgemm<1, 512, true><<<gE, 512, 0, stream>>>(nullptr, nullptr, yb, buf1, he_tgt, he_w,
                                                    Wgt, b_gate, yb, nullptr, E);
        // out = clip(y @ Wu + b)      (yb linear -> d_out fp32)
        wgemm<3, 256, true><<<gR, 512, 0, stream>>>(yb, nullptr, nullptr, nullptr, nullptr, nullptr,
                                                    Wut, b_upd, nullptr, (float*)d_out, R);
    } else {
        char* ws = (char*)d_ws;
        ushort_t* buf0 = (ushort_t*)ws;
        ushort_t* buf1 = buf0 + (size_t)E * H;
        int*      imap = (int*)(buf1 + (size_t)E * H);
        ushort_t* Wmt  = (ushort_t*)((char*)imap + (size_t)R * 4);
        ushort_t* Wgt  = Wmt + 256 * 256;
        ushort_t* Wut  = Wgt + 256 * 512;

        prep_all<<<2048, 256, 0, stream>>>(W_msg, W_gate, W_upd, x,
                                           Wmt, Wgt, Wut, imap, (ushort_t*)nullptr, R, 0);
        imap_scatter<<<(E + 255) / 256, 256, 0, stream>>>(he_tgt, imap, E);
        seg_mean_f32w<<<(E + 3) / 4, 256, 0, stream>>>(x, he_ptr, he_src, buf0, E);

        wgemm<0, 256, false><<<gE, 512, 0, stream>>>(buf0, nullptr, nullptr, nullptr, nullptr, nullptr,
                                                     Wmt, b_msg, buf1, nullptr, E);
        wgemm<1, 512, false><<<gE, 512, 0, stream>>>(nullptr, x, nullptr, buf1, he_tgt, he_w,
                                                     Wgt, b_gate, buf0, nullptr, E);
        wgemm<2, 256, false><<<gR, 512, 0, stream>>>(nullptr, x, nullptr, buf0, imap, nullptr,
                                                     Wut, b_upd, nullptr, (float*)d_out, R);
    }
}

// Round 11
// 350.797 us; speedup vs baseline: 3.5130x; 1.0186x over previous
//
#include <hip/hip_runtime.h>
#include <math.h>

#define H 256

typedef __attribute__((ext_vector_type(8))) short short8;
typedef __attribute__((ext_vector_type(4))) float f32x4;
typedef __attribute__((ext_vector_type(4))) int int4v;
typedef __attribute__((ext_vector_type(2))) unsigned int uint2v;
typedef unsigned short ushort_t;

__device__ __forceinline__ float bf2f(unsigned short u) {
    union { unsigned int i; float f; } v; v.i = ((unsigned int)u) << 16; return v.f;
}
__device__ __forceinline__ unsigned short f2bf(float f) {
    union { float f; unsigned int i; } v; v.f = f;
    unsigned int r = v.i + 0x7FFFu + ((v.i >> 16) & 1u);   // RNE
    return (unsigned short)(r >> 16);
}
__device__ __forceinline__ void glds16(const void* g, void* l) {
    __builtin_amdgcn_global_load_lds((const __attribute__((address_space(1))) void*)g,
                                     (__attribute__((address_space(3))) void*)l, 16, 0, 0);
}
__device__ __forceinline__ int4v pack_f32x8_bf16(const float* p) {
    float4 f0 = *(const float4*)(p);
    float4 f1 = *(const float4*)(p + 4);
    int4v d;
    d.x = (int)((unsigned)f2bf(f0.x) | ((unsigned)f2bf(f0.y) << 16));
    d.y = (int)((unsigned)f2bf(f0.z) | ((unsigned)f2bf(f0.w) << 16));
    d.z = (int)((unsigned)f2bf(f1.x) | ((unsigned)f2bf(f1.y) << 16));
    d.w = (int)((unsigned)f2bf(f1.z) | ((unsigned)f2bf(f1.w) << 16));
    return d;
}

// ---------------- fused prep: weights transpose+cast, (opt) imap init, x->bf16 ----------------
__global__ void prep_all(const float* __restrict__ Wm, const float* __restrict__ Wg,
                         const float* __restrict__ Wu, const float* __restrict__ x,
                         ushort_t* __restrict__ Wmt, ushort_t* __restrict__ Wgt,
                         ushort_t* __restrict__ Wut, int* __restrict__ imap,
                         ushort_t* __restrict__ yb, int R, size_t n8) {
    size_t gtid = (size_t)blockIdx.x * blockDim.x + threadIdx.x;
    size_t stride = (size_t)gridDim.x * blockDim.x;
    for (size_t i = gtid; i < 65536; i += stride) {
        int n = (int)(i >> 8), k = (int)(i & 255);
        Wmt[i] = f2bf(Wm[(size_t)k * 256 + n]);
        Wut[i] = f2bf(Wu[(size_t)k * 256 + n]);
    }
    for (size_t i = gtid; i < 131072; i += stride) {
        int n = (int)(i >> 9), k = (int)(i & 511);
        Wgt[i] = f2bf(Wg[(size_t)k * 256 + n]);
    }
    if (imap) for (size_t i = gtid; i < (size_t)R; i += stride) imap[i] = -1;
    if (yb) for (size_t i = gtid; i < n8; i += stride)
        *(int4v*)(yb + i * 8) = pack_f32x8_bf16(x + i * 8);
}

__global__ void imap_scatter(const int* __restrict__ tgt, int* __restrict__ imap, int E) {
    int e = blockIdx.x * 256 + threadIdx.x;
    if (e < E) imap[tgt[e]] = e;
}

// ---------------- segment mean: half-wave per edge, 16B/lane, unroll-4 ----------------
// 8 edges per 256-thread block; lane (0..31) owns 8 cols; each row read is
// 32 lanes x 16B = 512B fully coalesced. Load insts per edge-pair = max(dA,dB)
// (vs dA+dB at wave-per-edge), 2x bytes in flight per lane. Divergence between
// half-waves handled by exec mask (VALU ~9% busy -> free).
__global__ __launch_bounds__(256) void seg_mean_bf16(const ushort_t* __restrict__ yb,
                                                     const int* __restrict__ ptr,
                                                     const int* __restrict__ src,
                                                     ushort_t* __restrict__ smb, int E) {
    int e = blockIdx.x * 8 + (threadIdx.x >> 5);
    if (e >= E) return;
    int lane = threadIdx.x & 31;
    const ushort_t* base = yb + lane * 8;
    int s = ptr[e], t = ptr[e + 1];
    float a0 = 0.f, a1 = 0.f, a2 = 0.f, a3 = 0.f, a4 = 0.f, a5 = 0.f, a6 = 0.f, a7 = 0.f;
    int i = s;
    for (; i + 4 <= t; i += 4) {
        int4v v0 = *(const int4v*)(base + (size_t)src[i + 0] * H);
        int4v v1 = *(const int4v*)(base + (size_t)src[i + 1] * H);
        int4v v2 = *(const int4v*)(base + (size_t)src[i + 2] * H);
        int4v v3 = *(const int4v*)(base + (size_t)src[i + 3] * H);
        a0 += bf2f((unsigned)v0.x & 0xffff) + bf2f((unsigned)v1.x & 0xffff) + bf2f((unsigned)v2.x & 0xffff) + bf2f((unsigned)v3.x & 0xffff);
        a1 += bf2f((unsigned)v0.x >> 16)    + bf2f((unsigned)v1.x >> 16)    + bf2f((unsigned)v2.x >> 16)    + bf2f((unsigned)v3.x >> 16);
        a2 += bf2f((unsigned)v0.y & 0xffff) + bf2f((unsigned)v1.y & 0xffff) + bf2f((unsigned)v2.y & 0xffff) + bf2f((unsigned)v3.y & 0xffff);
        a3 += bf2f((unsigned)v0.y >> 16)    + bf2f((unsigned)v1.y >> 16)    + bf2f((unsigned)v2.y >> 16)    + bf2f((unsigned)v3.y >> 16);
        a4 += bf2f((unsigned)v0.z & 0xffff) + bf2f((unsigned)v1.z & 0xffff) + bf2f((unsigned)v2.z & 0xffff) + bf2f((unsigned)v3.z & 0xffff);
        a5 += bf2f((unsigned)v0.z >> 16)    + bf2f((unsigned)v1.z >> 16)    + bf2f((unsigned)v2.z >> 16)    + bf2f((unsigned)v3.z >> 16);
        a6 += bf2f((unsigned)v0.w & 0xffff) + bf2f((unsigned)v1.w & 0xffff) + bf2f((unsigned)v2.w & 0xffff) + bf2f((unsigned)v3.w & 0xffff);
        a7 += bf2f((unsigned)v0.w >> 16)    + bf2f((unsigned)v1.w >> 16)    + bf2f((unsigned)v2.w >> 16)    + bf2f((unsigned)v3.w >> 16);
    }
    for (; i < t; ++i) {
        int4v v = *(const int4v*)(base + (size_t)src[i] * H);
        a0 += bf2f((unsigned)v.x & 0xffff); a1 += bf2f((unsigned)v.x >> 16);
        a2 += bf2f((unsigned)v.y & 0xffff); a3 += bf2f((unsigned)v.y >> 16);
        a4 += bf2f((unsigned)v.z & 0xffff); a5 += bf2f((unsigned)v.z >> 16);
        a6 += bf2f((unsigned)v.w & 0xffff); a7 += bf2f((unsigned)v.w >> 16);
    }
    float inv = 1.f / (float)(t - s);
    int4v o;
    o.x = (int)((unsigned)f2bf(a0 * inv) | ((unsigned)f2bf(a1 * inv) << 16));
    o.y = (int)((unsigned)f2bf(a2 * inv) | ((unsigned)f2bf(a3 * inv) << 16));
    o.z = (int)((unsigned)f2bf(a4 * inv) | ((unsigned)f2bf(a5 * inv) << 16));
    o.w = (int)((unsigned)f2bf(a6 * inv) | ((unsigned)f2bf(a7 * inv) << 16));
    *(int4v*)(smb + (size_t)e * H + lane * 8) = o;
}

// fallback: fp32 gather (small-ws path)
__global__ __launch_bounds__(256) void seg_mean_f32w(const float* __restrict__ x,
                                                     const int* __restrict__ ptr,
                                                     const int* __restrict__ src,
                                                     ushort_t* __restrict__ smb, int E) {
    int e = blockIdx.x * 4 + (threadIdx.x >> 6);
    if (e >= E) return;
    int lane = threadIdx.x & 63;
    int s = ptr[e], t = ptr[e + 1];
    float a0 = 0.f, a1 = 0.f, a2 = 0.f, a3 = 0.f;
    int i = s;
    for (; i + 4 <= t; i += 4) {
        float4 v0 = *(const float4*)(x + (size_t)src[i + 0] * H + lane * 4);
        float4 v1 = *(const float4*)(x + (size_t)src[i + 1] * H + lane * 4);
        float4 v2 = *(const float4*)(x + (size_t)src[i + 2] * H + lane * 4);
        float4 v3 = *(const float4*)(x + (size_t)src[i + 3] * H + lane * 4);
        a0 += v0.x + v1.x + v2.x + v3.x;
        a1 += v0.y + v1.y + v2.y + v3.y;
        a2 += v0.z + v1.z + v2.z + v3.z;
        a3 += v0.w + v1.w + v2.w + v3.w;
    }
    for (; i < t; ++i) {
        float4 v = *(const float4*)(x + (size_t)src[i] * H + lane * 4);
        a0 += v.x; a1 += v.y; a2 += v.z; a3 += v.w;
    }
    float inv = 1.f / (float)(t - s);
    uint2v o;
    o.x = (unsigned)f2bf(a0 * inv) | ((unsigned)f2bf(a1 * inv) << 16);
    o.y = (unsigned)f2bf(a2 * inv) | ((unsigned)f2bf(a3 * inv) << 16);
    *(uint2v*)(smb + (size_t)e * H + lane * 4) = o;
}

// reg-stage chunk loader for the fp32 fallback path only
#define LOADA_CHUNK_F(k0v, d)                                                            \
    do {                                                                                 \
        if constexpr (MODE == 1) {                                                       \
            if ((k0v) < 256) d = pack_f32x8_bf16(pXf + (k0v));                           \
            else             d = *(const int4v*)(pA + ((k0v) - 256));                    \
        } else {                                                                         \
            if (!useF) d = *(const int4v*)(p2 + (k0v));                                  \
            else       d = pack_f32x8_bf16(p2f + (k0v));                                 \
        }                                                                                \
    } while (0)

// ---------------- full-N MFMA GEMM (8 waves, 128x256 tile, T14 K-loop) ----------------
// MODE 0: A = Abf rows (glds16 linear).  Epi: OutB = bf16(z + bias).
// MODE 1: A row e = [x[tgt[e]] | Aux[e]] (KTOT=512).
//         Epi: g=sigmoid(z+bias); u = tx + hew*g*m.
//         XB=true: scatter u into OutB[tgt[e]] (tgt injective, tiles partition e
//                  -> no cross-block row aliasing; rows are 512B-aligned).
//         XB=false: OutB[e] (fallback).
// MODE 2: fallback imap path: A row r = Idx[r]>=0 ? Aux[Idx[r]] : x[r]; fp32 clip.
// MODE 3: A = Abf rows (glds16 linear).  Epi: OutF = clip(z+bias,0,1) fp32.
template<int MODE, int KTOT, bool XB>
__global__ __launch_bounds__(512, 4) void wgemm(
    const ushort_t* __restrict__ Abf,
    const float* __restrict__ Xf,
    const ushort_t* __restrict__ Xb,
    const ushort_t* __restrict__ Aux,
    const int* __restrict__ Idx,
    const float* __restrict__ Hew,
    const ushort_t* __restrict__ Wt,     // [256][KTOT] bf16 (pre-transposed)
    const float* __restrict__ Bias,      // [256] fp32
    ushort_t* __restrict__ OutB,
    float* __restrict__ OutF,
    int M)
{
    constexpr int NT = KTOT / 32;
    const int m0 = blockIdx.x * 128;
    const int tid = threadIdx.x;
    const int wv = tid >> 6;
    const int lane = tid & 63;
    const int wr = wv >> 2, wc = wv & 3;    // waves 2 (rows) x 4 (cols)

    __shared__ __align__(16) ushort_t As[2][128 * 32];   // 16 KiB
    __shared__ __align__(16) ushort_t Bs[2][256 * 32];   // 32 KiB

    // ---- staging geometry (swizzle verified conflict-free in round 7) ----
    const int aRow  = tid >> 2;             // 0..127
    const int sl    = tid & 3;
    const int aCc   = sl ^ ((aRow >> 1) & 3);
    const int bCol0 = tid >> 2;
    const int bCol1 = bCol0 + 128;
    const int bCc0  = sl ^ ((bCol0 >> 1) & 3);
    const int bCc1  = sl ^ ((bCol1 >> 1) & 3);

    const ushort_t* bSrc0 = Wt + (size_t)bCol0 * KTOT + bCc0 * 8;
    const ushort_t* bSrc1 = Wt + (size_t)bCol1 * KTOT + bCc1 * 8;

    int r = m0 + aRow; if (r > M - 1) r = M - 1;

    // per-lane A source pointers
    const ushort_t* aP0 = nullptr;          // k domain [0,256)
    const ushort_t* aP1 = nullptr;          // k domain [256,512) (MODE1 only)
    const float* pXf = nullptr; const ushort_t* pA = nullptr;   // fp32 fallback
    const ushort_t* p2 = nullptr; const float* p2f = nullptr;
    bool useF = false;
    if constexpr (MODE == 0 || MODE == 3) {
        aP0 = Abf + (size_t)r * KTOT + aCc * 8;
    } else if constexpr (MODE == 1) {
        int tr = Idx[r];
        if constexpr (XB) {
            aP0 = Xb + (size_t)tr * 256 + aCc * 8;
            aP1 = Aux + (size_t)r * 256 + aCc * 8 - 256;   // +k0 with k0>=256 lands right
        } else {
            pXf = Xf + (size_t)tr * 256 + aCc * 8;
            pA  = Aux + (size_t)r * 256 + aCc * 8;
        }
    } else {
        int e = Idx[r];
        if (e >= 0) { p2 = Aux + (size_t)e * 256 + aCc * 8; useF = false; }
        else        { p2f = Xf + (size_t)r * 256 + aCc * 8; useF = true; }
    }

    f32x4 acc[4][4];
#pragma unroll
    for (int i = 0; i < 4; ++i)
#pragma unroll
        for (int j = 0; j < 4; ++j) acc[i][j] = (f32x4){0.f, 0.f, 0.f, 0.f};

    // ---- prologue: stage tile 0 ----
    glds16(bSrc0, (char*)&Bs[0][0] + tid * 16);
    glds16(bSrc1, (char*)&Bs[0][0] + (tid + 512) * 16);
    if constexpr (MODE == 0 || MODE == 3 || (MODE == 1 && XB)) {
        glds16(aP0, (char*)&As[0][0] + tid * 16);
    } else {
        int4v d0; LOADA_CHUNK_F(0, d0);
        *(int4v*)((char*)&As[0][0] + tid * 16) = d0;
    }

    // ---- K loop: one barrier per step ----
#pragma unroll 2
    for (int kt = 0; kt < NT; ++kt) {
        __syncthreads();                      // drains stage(kt): issued one compute-phase ago
        const int cur = kt & 1;
        const int nxt = cur ^ 1;
        const bool more = (kt + 1 < NT);
        int4v pf;
        if (more) {
            const int k0 = (kt + 1) * 32;
            glds16(bSrc0 + k0, (char*)&Bs[nxt][0] + tid * 16);
            glds16(bSrc1 + k0, (char*)&Bs[nxt][0] + (tid + 512) * 16);
            if constexpr (MODE == 0 || MODE == 3) {
                glds16(aP0 + k0, (char*)&As[nxt][0] + tid * 16);
            } else if constexpr (MODE == 1 && XB) {
                const ushort_t* s = (k0 < 256) ? (aP0 + k0) : (aP1 + k0);
                glds16(s, (char*)&As[nxt][0] + tid * 16);
            } else {
                LOADA_CHUNK_F(k0, pf);        // issue only; wait lands after MFMAs
            }
        }

        // fragments: swizzle-matched reads (2-way = free)
        const char* aBase = (const char*)&As[cur][0];
        const char* bBase = (const char*)&Bs[cur][0];
        const int kg = lane >> 4;
        short8 a0, a1, a2, a3;
        {
            int r0 = wr * 64 + 0 * 16 + (lane & 15);
            int r1 = r0 + 16, r2 = r0 + 32, r3 = r0 + 48;
            a0 = *(const short8*)(aBase + (r0 * 4 + (kg ^ ((r0 >> 1) & 3))) * 16);
            a1 = *(const short8*)(aBase + (r1 * 4 + (kg ^ ((r1 >> 1) & 3))) * 16);
            a2 = *(const short8*)(aBase + (r2 * 4 + (kg ^ ((r2 >> 1) & 3))) * 16);
            a3 = *(const short8*)(aBase + (r3 * 4 + (kg ^ ((r3 >> 1) & 3))) * 16);
        }
#pragma unroll
        for (int fn = 0; fn < 4; ++fn) {
            int cn = wc * 64 + fn * 16 + (lane & 15);
            short8 b = *(const short8*)(bBase + (cn * 4 + (kg ^ ((cn >> 1) & 3))) * 16);
            acc[0][fn] = __builtin_amdgcn_mfma_f32_16x16x32_bf16(a0, b, acc[0][fn], 0, 0, 0);
            acc[1][fn] = __builtin_amdgcn_mfma_f32_16x16x32_bf16(a1, b, acc[1][fn], 0, 0, 0);
            acc[2][fn] = __builtin_amdgcn_mfma_f32_16x16x32_bf16(a2, b, acc[2][fn], 0, 0, 0);
            acc[3][fn] = __builtin_amdgcn_mfma_f32_16x16x32_bf16(a3, b, acc[3][fn], 0, 0, 0);
        }
        if (more) {
            if constexpr (MODE == 2 || (MODE == 1 && !XB)) {
                *(int4v*)((char*)&As[nxt][0] + tid * 16) = pf;   // vmcnt wait covered by MFMAs
            }
        }
    }

    // ---- epilogue: C/D layout col=lane&15, row=(lane>>4)*4+i ----
#pragma unroll
    for (int fm = 0; fm < 4; ++fm) {
        int rbase = m0 + wr * 64 + fm * 16 + (lane >> 4) * 4;
#pragma unroll
        for (int fn = 0; fn < 4; ++fn) {
            int col = wc * 64 + fn * 16 + (lane & 15);
            float bia = Bias[col];
            f32x4 v = acc[fm][fn];
#pragma unroll
            for (int i = 0; i < 4; ++i) {
                int rg = rbase + i;
                if (rg < M) {
                    float z = v[i] + bia;
                    if constexpr (MODE == 0) {
                        OutB[(size_t)rg * 256 + col] = f2bf(z);
                    } else if constexpr (MODE == 1) {
                        float g = 1.f / (1.f + __expf(-z));
                        int tr = Idx[rg];
                        float tx;
                        if constexpr (XB) tx = bf2f(Xb[(size_t)tr * 256 + col]);
                        else              tx = Xf[(size_t)tr * 256 + col];
                        float m = bf2f(Aux[(size_t)rg * 256 + col]);
                        float u = tx + Hew[rg] * g * m;
                        if constexpr (XB) OutB[(size_t)tr * 256 + col] = f2bf(u);   // scatter into yb
                        else              OutB[(size_t)rg * 256 + col] = f2bf(u);
                    } else {
                        OutF[(size_t)rg * 256 + col] = fminf(fmaxf(z, 0.f), 1.f);
                    }
                }
            }
        }
    }
}

extern "C" void kernel_launch(void* const* d_in, const int* in_sizes, int n_in,
                              void* d_out, int out_size, void* d_ws, size_t ws_size,
                              hipStream_t stream) {
    const float* x      = (const float*)d_in[0];
    const int*   he_ptr = (const int*)d_in[1];
    const int*   he_src = (const int*)d_in[2];
    const int*   he_tgt = (const int*)d_in[3];
    const float* he_w   = (const float*)d_in[4];
    const float* W_msg  = (const float*)d_in[5];
    const float* b_msg  = (const float*)d_in[6];
    const float* W_gate = (const float*)d_in[7];
    const float* b_gate = (const float*)d_in[8];
    const float* W_upd  = (const float*)d_in[9];
    const float* b_upd  = (const float*)d_in[10];

    const int E = in_sizes[3];
    const int R = in_sizes[0] / H;

    const size_t wbytes = (size_t)(65536 + 131072 + 65536) * 2;
    const size_t needA = (size_t)R * H * 2 + (size_t)E * H * 2 * 2 + (size_t)R * 4 + wbytes;
    const bool bigws = ws_size >= needA;

    const int gE = (E + 127) / 128;
    const int gR = (R + 127) / 128;

    if (bigws) {
        char* ws = (char*)d_ws;
        ushort_t* yb   = (ushort_t*)ws;                                // R*256 bf16(x); becomes y after gemm2
        ushort_t* buf0 = yb + (size_t)R * H;                           // E*256: smb
        ushort_t* buf1 = buf0 + (size_t)E * H;                         // E*256: msgb
        ushort_t* Wmt  = (ushort_t*)(buf1 + (size_t)E * H);
        ushort_t* Wgt  = Wmt + 256 * 256;
        ushort_t* Wut  = Wgt + 256 * 512;

        prep_all<<<2048, 256, 0, stream>>>(W_msg, W_gate, W_upd, x,
                                           Wmt, Wgt, Wut, (int*)nullptr, yb, R, (size_t)R * H / 8);
        seg_mean_bf16<<<(E + 7) / 8, 256, 0, stream>>>(yb, he_ptr, he_src, buf0, E);

        // msg = smb @ Wm + b          (buf0 -> buf1)
        wgemm<0, 256, true><<<gE, 512, 0, stream>>>(buf0, nullptr, yb, nullptr, nullptr, nullptr,
                                                    Wmt, b_msg, buf1, nullptr, E);
        // gate + gated residual; u scattered into yb[tgt[e]]  -> yb becomes y
        wgemm<1, 512, true><<<gE, 512, 0, stream>>>(nullptr, nullptr, yb, buf1, he_tgt, he_w,
                                                    Wgt, b_gate, yb, nullptr, E);
        // out = clip(y @ Wu + b)      (yb linear -> d_out fp32)
        wgemm<3, 256, true><<<gR, 512, 0, stream>>>(yb, nullptr, nullptr, nullptr, nullptr, nullptr,
                                                    Wut, b_upd, nullptr, (float*)d_out, R);
    } else {
        char* ws = (char*)d_ws;
        ushort_t* buf0 = (ushort_t*)ws;
        ushort_t* buf1 = buf0 + (size_t)E * H;
        int*      imap = (int*)(buf1 + (size_t)E * H);
        ushort_t* Wmt  = (ushort_t*)((char*)imap + (size_t)R * 4);
        ushort_t* Wgt  = Wmt + 256 * 256;
        ushort_t* Wut  = Wgt + 256 * 512;

        prep_all<<<2048, 256, 0, stream>>>(W_msg, W_gate, W_upd, x,
                                           Wmt, Wgt, Wut, imap, (ushort_t*)nullptr, R, 0);
        imap_scatter<<<(E + 255) / 256, 256, 0, stream>>>(he_tgt, imap, E);
        seg_mean_f32w<<<(E + 3) / 4, 256, 0, stream>>>(x, he_ptr, he_src, buf0, E);

        wgemm<0, 256, false><<<gE, 512, 0, stream>>>(buf0, nullptr, nullptr, nullptr, nullptr, nullptr,
                                                     Wmt, b_msg, buf1, nullptr, E);
        wgemm<1, 512, false><<<gE, 512, 0, stream>>>(nullptr, x, nullptr, buf1, he_tgt, he_w,
                                                     Wgt, b_gate, buf0, nullptr, E);
        wgemm<2, 256, false><<<gR, 512, 0, stream>>>(nullptr, x, nullptr, buf0, imap, nullptr,
                                                     Wut, b_upd, nullptr, (float*)d_out, R);
    }
}

// Round 12
// 345.962 us; speedup vs baseline: 3.5621x; 1.0140x over previous
//
#include <hip/hip_runtime.h>
#include <math.h>

#define H 256

typedef __attribute__((ext_vector_type(8))) short short8;
typedef __attribute__((ext_vector_type(4))) float f32x4;
typedef __attribute__((ext_vector_type(4))) int int4v;
typedef __attribute__((ext_vector_type(2))) unsigned int uint2v;
typedef unsigned short ushort_t;

__device__ __forceinline__ float bf2f(unsigned short u) {
    union { unsigned int i; float f; } v; v.i = ((unsigned int)u) << 16; return v.f;
}
__device__ __forceinline__ unsigned short f2bf(float f) {
    union { float f; unsigned int i; } v; v.f = f;
    unsigned int r = v.i + 0x7FFFu + ((v.i >> 16) & 1u);   // RNE
    return (unsigned short)(r >> 16);
}
__device__ __forceinline__ void glds16(const void* g, void* l) {
    __builtin_amdgcn_global_load_lds((const __attribute__((address_space(1))) void*)g,
                                     (__attribute__((address_space(3))) void*)l, 16, 0, 0);
}
__device__ __forceinline__ int4v pack_f32x8_bf16(const float* p) {
    float4 f0 = *(const float4*)(p);
    float4 f1 = *(const float4*)(p + 4);
    int4v d;
    d.x = (int)((unsigned)f2bf(f0.x) | ((unsigned)f2bf(f0.y) << 16));
    d.y = (int)((unsigned)f2bf(f0.z) | ((unsigned)f2bf(f0.w) << 16));
    d.z = (int)((unsigned)f2bf(f1.x) | ((unsigned)f2bf(f1.y) << 16));
    d.w = (int)((unsigned)f2bf(f1.z) | ((unsigned)f2bf(f1.w) << 16));
    return d;
}

// ---------------- fused prep: weights transpose+cast, (opt) imap init, x->bf16 ----------------
__global__ void prep_all(const float* __restrict__ Wm, const float* __restrict__ Wg,
                         const float* __restrict__ Wu, const float* __restrict__ x,
                         ushort_t* __restrict__ Wmt, ushort_t* __restrict__ Wgt,
                         ushort_t* __restrict__ Wut, int* __restrict__ imap,
                         ushort_t* __restrict__ yb, int R, size_t n8) {
    size_t gtid = (size_t)blockIdx.x * blockDim.x + threadIdx.x;
    size_t stride = (size_t)gridDim.x * blockDim.x;
    for (size_t i = gtid; i < 65536; i += stride) {
        int n = (int)(i >> 8), k = (int)(i & 255);
        Wmt[i] = f2bf(Wm[(size_t)k * 256 + n]);
        Wut[i] = f2bf(Wu[(size_t)k * 256 + n]);
    }
    for (size_t i = gtid; i < 131072; i += stride) {
        int n = (int)(i >> 9), k = (int)(i & 511);
        Wgt[i] = f2bf(Wg[(size_t)k * 256 + n]);
    }
    if (imap) for (size_t i = gtid; i < (size_t)R; i += stride) imap[i] = -1;
    if (yb) for (size_t i = gtid; i < n8; i += stride)
        *(int4v*)(yb + i * 8) = pack_f32x8_bf16(x + i * 8);
}

__global__ void imap_scatter(const int* __restrict__ tgt, int* __restrict__ imap, int E) {
    int e = blockIdx.x * 256 + threadIdx.x;
    if (e < E) imap[tgt[e]] = e;
}

// ---------------- segment mean: half-wave per edge, 16B/lane, unroll-4 ----------------
__global__ __launch_bounds__(256) void seg_mean_bf16(const ushort_t* __restrict__ yb,
                                                     const int* __restrict__ ptr,
                                                     const int* __restrict__ src,
                                                     ushort_t* __restrict__ smb, int E) {
    int e = blockIdx.x * 8 + (threadIdx.x >> 5);
    if (e >= E) return;
    int lane = threadIdx.x & 31;
    const ushort_t* base = yb + lane * 8;
    int s = ptr[e], t = ptr[e + 1];
    float a0 = 0.f, a1 = 0.f, a2 = 0.f, a3 = 0.f, a4 = 0.f, a5 = 0.f, a6 = 0.f, a7 = 0.f;
    int i = s;
    for (; i + 4 <= t; i += 4) {
        int4v v0 = *(const int4v*)(base + (size_t)src[i + 0] * H);
        int4v v1 = *(const int4v*)(base + (size_t)src[i + 1] * H);
        int4v v2 = *(const int4v*)(base + (size_t)src[i + 2] * H);
        int4v v3 = *(const int4v*)(base + (size_t)src[i + 3] * H);
        a0 += bf2f((unsigned)v0.x & 0xffff) + bf2f((unsigned)v1.x & 0xffff) + bf2f((unsigned)v2.x & 0xffff) + bf2f((unsigned)v3.x & 0xffff);
        a1 += bf2f((unsigned)v0.x >> 16)    + bf2f((unsigned)v1.x >> 16)    + bf2f((unsigned)v2.x >> 16)    + bf2f((unsigned)v3.x >> 16);
        a2 += bf2f((unsigned)v0.y & 0xffff) + bf2f((unsigned)v1.y & 0xffff) + bf2f((unsigned)v2.y & 0xffff) + bf2f((unsigned)v3.y & 0xffff);
        a3 += bf2f((unsigned)v0.y >> 16)    + bf2f((unsigned)v1.y >> 16)    + bf2f((unsigned)v2.y >> 16)    + bf2f((unsigned)v3.y >> 16);
        a4 += bf2f((unsigned)v0.z & 0xffff) + bf2f((unsigned)v1.z & 0xffff) + bf2f((unsigned)v2.z & 0xffff) + bf2f((unsigned)v3.z & 0xffff);
        a5 += bf2f((unsigned)v0.z >> 16)    + bf2f((unsigned)v1.z >> 16)    + bf2f((unsigned)v2.z >> 16)    + bf2f((unsigned)v3.z >> 16);
        a6 += bf2f((unsigned)v0.w & 0xffff) + bf2f((unsigned)v1.w & 0xffff) + bf2f((unsigned)v2.w & 0xffff) + bf2f((unsigned)v3.w & 0xffff);
        a7 += bf2f((unsigned)v0.w >> 16)    + bf2f((unsigned)v1.w >> 16)    + bf2f((unsigned)v2.w >> 16)    + bf2f((unsigned)v3.w >> 16);
    }
    for (; i < t; ++i) {
        int4v v = *(const int4v*)(base + (size_t)src[i] * H);
        a0 += bf2f((unsigned)v.x & 0xffff); a1 += bf2f((unsigned)v.x >> 16);
        a2 += bf2f((unsigned)v.y & 0xffff); a3 += bf2f((unsigned)v.y >> 16);
        a4 += bf2f((unsigned)v.z & 0xffff); a5 += bf2f((unsigned)v.z >> 16);
        a6 += bf2f((unsigned)v.w & 0xffff); a7 += bf2f((unsigned)v.w >> 16);
    }
    float inv = 1.f / (float)(t - s);
    int4v o;
    o.x = (int)((unsigned)f2bf(a0 * inv) | ((unsigned)f2bf(a1 * inv) << 16));
    o.y = (int)((unsigned)f2bf(a2 * inv) | ((unsigned)f2bf(a3 * inv) << 16));
    o.z = (int)((unsigned)f2bf(a4 * inv) | ((unsigned)f2bf(a5 * inv) << 16));
    o.w = (int)((unsigned)f2bf(a6 * inv) | ((unsigned)f2bf(a7 * inv) << 16));
    *(int4v*)(smb + (size_t)e * H + lane * 8) = o;
}

// fallback: fp32 gather (small-ws path)
__global__ __launch_bounds__(256) void seg_mean_f32w(const float* __restrict__ x,
                                                     const int* __restrict__ ptr,
                                                     const int* __restrict__ src,
                                                     ushort_t* __restrict__ smb, int E) {
    int e = blockIdx.x * 4 + (threadIdx.x >> 6);
    if (e >= E) return;
    int lane = threadIdx.x & 63;
    int s = ptr[e], t = ptr[e + 1];
    float a0 = 0.f, a1 = 0.f, a2 = 0.f, a3 = 0.f;
    int i = s;
    for (; i + 4 <= t; i += 4) {
        float4 v0 = *(const float4*)(x + (size_t)src[i + 0] * H + lane * 4);
        float4 v1 = *(const float4*)(x + (size_t)src[i + 1] * H + lane * 4);
        float4 v2 = *(const float4*)(x + (size_t)src[i + 2] * H + lane * 4);
        float4 v3 = *(const float4*)(x + (size_t)src[i + 3] * H + lane * 4);
        a0 += v0.x + v1.x + v2.x + v3.x;
        a1 += v0.y + v1.y + v2.y + v3.y;
        a2 += v0.z + v1.z + v2.z + v3.z;
        a3 += v0.w + v1.w + v2.w + v3.w;
    }
    for (; i < t; ++i) {
        float4 v = *(const float4*)(x + (size_t)src[i] * H + lane * 4);
        a0 += v.x; a1 += v.y; a2 += v.z; a3 += v.w;
    }
    float inv = 1.f / (float)(t - s);
    uint2v o;
    o.x = (unsigned)f2bf(a0 * inv) | ((unsigned)f2bf(a1 * inv) << 16);
    o.y = (unsigned)f2bf(a2 * inv) | ((unsigned)f2bf(a3 * inv) << 16);
    *(uint2v*)(smb + (size_t)e * H + lane * 4) = o;
}

// reg-stage chunk loader for the fp32 fallback path only
#define LOADA_CHUNK_F(k0v, d)                                                            \
    do {                                                                                 \
        if constexpr (MODE == 1) {                                                       \
            if ((k0v) < 256) d = pack_f32x8_bf16(pXf + (k0v));                           \
            else             d = *(const int4v*)(pA + ((k0v) - 256));                    \
        } else {                                                                         \
            if (!useF) d = *(const int4v*)(p2 + (k0v));                                  \
            else       d = pack_f32x8_bf16(p2f + (k0v));                                 \
        }                                                                                \
    } while (0)

// stage one K-tile (3 glds16) into ring buffer bufv  [GL modes only]
#define STAGE_GL(k0v, bufv)                                                              \
    do {                                                                                 \
        glds16(bSrc0 + (k0v), (char*)&Bs[bufv][0] + tid * 16);                           \
        glds16(bSrc1 + (k0v), (char*)&Bs[bufv][0] + (tid + 512) * 16);                   \
        if constexpr (MODE == 1) {                                                       \
            const ushort_t* s_ = ((k0v) < 256) ? (aP0 + (k0v)) : (aP1 + (k0v));          \
            glds16(s_, (char*)&As[bufv][0] + tid * 16);                                  \
        } else {                                                                         \
            glds16(aP0 + (k0v), (char*)&As[bufv][0] + tid * 16);                         \
        }                                                                                \
    } while (0)

// one K-tile of MFMAs from ring buffer bufv
#define COMPUTE_GL(bufv)                                                                 \
    do {                                                                                 \
        const char* aBase = (const char*)&As[bufv][0];                                   \
        const char* bBase = (const char*)&Bs[bufv][0];                                   \
        const int kg = lane >> 4;                                                        \
        short8 a0, a1, a2, a3;                                                           \
        int r0 = wr * 64 + (lane & 15);                                                  \
        int r1 = r0 + 16, r2 = r0 + 32, r3 = r0 + 48;                                    \
        a0 = *(const short8*)(aBase + (r0 * 4 + (kg ^ ((r0 >> 1) & 3))) * 16);           \
        a1 = *(const short8*)(aBase + (r1 * 4 + (kg ^ ((r1 >> 1) & 3))) * 16);           \
        a2 = *(const short8*)(aBase + (r2 * 4 + (kg ^ ((r2 >> 1) & 3))) * 16);           \
        a3 = *(const short8*)(aBase + (r3 * 4 + (kg ^ ((r3 >> 1) & 3))) * 16);           \
        _Pragma("unroll")                                                                \
        for (int fn = 0; fn < 4; ++fn) {                                                 \
            int cn = wc * 64 + fn * 16 + (lane & 15);                                    \
            short8 b = *(const short8*)(bBase + (cn * 4 + (kg ^ ((cn >> 1) & 3))) * 16); \
            acc[0][fn] = __builtin_amdgcn_mfma_f32_16x16x32_bf16(a0, b, acc[0][fn], 0, 0, 0); \
            acc[1][fn] = __builtin_amdgcn_mfma_f32_16x16x32_bf16(a1, b, acc[1][fn], 0, 0, 0); \
            acc[2][fn] = __builtin_amdgcn_mfma_f32_16x16x32_bf16(a2, b, acc[2][fn], 0, 0, 0); \
            acc[3][fn] = __builtin_amdgcn_mfma_f32_16x16x32_bf16(a3, b, acc[3][fn], 0, 0, 0); \
        }                                                                                \
    } while (0)

// ---------------- full-N MFMA GEMM (8 waves, 128x256 tile) ----------------
// GL modes (0/3, 1&XB): 3-buffer LDS ring + raw s_barrier + counted vmcnt(3):
//   [vmcnt(3); barrier; issue stage(kt+2); compute(kt)]
// stage(kt+1)'s 3 loads stay in flight across the barrier (T4); stage(kt+2)
// writes the buffer last read by compute(kt-1), finished before this barrier.
// Fallback modes keep the proven 2-buffer __syncthreads loop.
template<int MODE, int KTOT, bool XB>
__global__ __launch_bounds__(512, 4) void wgemm(
    const ushort_t* __restrict__ Abf,
    const float* __restrict__ Xf,
    const ushort_t* __restrict__ Xb,
    const ushort_t* __restrict__ Aux,
    const int* __restrict__ Idx,
    const float* __restrict__ Hew,
    const ushort_t* __restrict__ Wt,     // [256][KTOT] bf16 (pre-transposed)
    const float* __restrict__ Bias,      // [256] fp32
    ushort_t* __restrict__ OutB,
    float* __restrict__ OutF,
    int M)
{
    constexpr int NT = KTOT / 32;
    constexpr bool GL = (MODE == 0 || MODE == 3 || (MODE == 1 && XB));
    const int m0 = blockIdx.x * 128;
    const int tid = threadIdx.x;
    const int wv = tid >> 6;
    const int lane = tid & 63;
    const int wr = wv >> 2, wc = wv & 3;    // waves 2 (rows) x 4 (cols)

    __shared__ __align__(16) ushort_t As[3][128 * 32];   // 24 KiB (GL uses 3, fallback 2)
    __shared__ __align__(16) ushort_t Bs[3][256 * 32];   // 48 KiB

    // ---- staging geometry (swizzle verified conflict-free in round 7) ----
    const int aRow  = tid >> 2;             // 0..127
    const int sl    = tid & 3;
    const int aCc   = sl ^ ((aRow >> 1) & 3);
    const int bCol0 = tid >> 2;
    const int bCol1 = bCol0 + 128;
    const int bCc0  = sl ^ ((bCol0 >> 1) & 3);
    const int bCc1  = sl ^ ((bCol1 >> 1) & 3);

    const ushort_t* bSrc0 = Wt + (size_t)bCol0 * KTOT + bCc0 * 8;
    const ushort_t* bSrc1 = Wt + (size_t)bCol1 * KTOT + bCc1 * 8;

    int r = m0 + aRow; if (r > M - 1) r = M - 1;

    // per-lane A source pointers
    const ushort_t* aP0 = nullptr;          // k domain [0,256)
    const ushort_t* aP1 = nullptr;          // k domain [256,512) (MODE1 only)
    const float* pXf = nullptr; const ushort_t* pA = nullptr;   // fp32 fallback
    const ushort_t* p2 = nullptr; const float* p2f = nullptr;
    bool useF = false;
    if constexpr (MODE == 0 || MODE == 3) {
        aP0 = Abf + (size_t)r * KTOT + aCc * 8;
    } else if constexpr (MODE == 1) {
        int tr = Idx[r];
        if constexpr (XB) {
            aP0 = Xb + (size_t)tr * 256 + aCc * 8;
            aP1 = Aux + (size_t)r * 256 + aCc * 8 - 256;   // +k0 with k0>=256 lands right
        } else {
            pXf = Xf + (size_t)tr * 256 + aCc * 8;
            pA  = Aux + (size_t)r * 256 + aCc * 8;
        }
    } else {
        int e = Idx[r];
        if (e >= 0) { p2 = Aux + (size_t)e * 256 + aCc * 8; useF = false; }
        else        { p2f = Xf + (size_t)r * 256 + aCc * 8; useF = true; }
    }

    f32x4 acc[4][4];
#pragma unroll
    for (int i = 0; i < 4; ++i)
#pragma unroll
        for (int j = 0; j < 4; ++j) acc[i][j] = (f32x4){0.f, 0.f, 0.f, 0.f};

    if constexpr (GL) {
        // ---- prologue: stage tiles 0,1 (6 loads in flight) ----
        STAGE_GL(0, 0);
        STAGE_GL(32, 1);
        // ---- K loop: counted-vmcnt pipeline, fully unrolled ----
#pragma unroll
        for (int kt = 0; kt < NT; ++kt) {
            if (kt == NT - 1) asm volatile("s_waitcnt vmcnt(0)" ::: "memory");
            else              asm volatile("s_waitcnt vmcnt(3)" ::: "memory");
            __builtin_amdgcn_s_barrier();
            if (kt + 2 < NT) {
                const int k0 = (kt + 2) * 32;
                const int bn = (kt + 2) % 3;
                STAGE_GL(k0, bn);
            }
            COMPUTE_GL(kt % 3);
        }
    } else {
        // ---- fallback: 2-buffer __syncthreads loop (round-10 structure) ----
        {
            int4v d0; LOADA_CHUNK_F(0, d0);
            *(int4v*)((char*)&As[0][0] + tid * 16) = d0;
        }
        glds16(bSrc0, (char*)&Bs[0][0] + tid * 16);
        glds16(bSrc1, (char*)&Bs[0][0] + (tid + 512) * 16);
#pragma unroll 2
        for (int kt = 0; kt < NT; ++kt) {
            __syncthreads();
            const int cur = kt & 1;
            const int nxt = cur ^ 1;
            const bool more = (kt + 1 < NT);
            int4v pf;
            if (more) {
                const int k0 = (kt + 1) * 32;
                glds16(bSrc0 + k0, (char*)&Bs[nxt][0] + tid * 16);
                glds16(bSrc1 + k0, (char*)&Bs[nxt][0] + (tid + 512) * 16);
                LOADA_CHUNK_F(k0, pf);
            }
            COMPUTE_GL(cur);
            if (more) {
                *(int4v*)((char*)&As[nxt][0] + tid * 16) = pf;
            }
        }
    }

    // ---- epilogue: C/D layout col=lane&15, row=(lane>>4)*4+i ----
#pragma unroll
    for (int fm = 0; fm < 4; ++fm) {
        int rbase = m0 + wr * 64 + fm * 16 + (lane >> 4) * 4;
#pragma unroll
        for (int fn = 0; fn < 4; ++fn) {
            int col = wc * 64 + fn * 16 + (lane & 15);
            float bia = Bias[col];
            f32x4 v = acc[fm][fn];
#pragma unroll
            for (int i = 0; i < 4; ++i) {
                int rg = rbase + i;
                if (rg < M) {
                    float z = v[i] + bia;
                    if constexpr (MODE == 0) {
                        OutB[(size_t)rg * 256 + col] = f2bf(z);
                    } else if constexpr (MODE == 1) {
                        float g = 1.f / (1.f + __expf(-z));
                        int tr = Idx[rg];
                        float tx;
                        if constexpr (XB) tx = bf2f(Xb[(size_t)tr * 256 + col]);
                        else              tx = Xf[(size_t)tr * 256 + col];
                        float m = bf2f(Aux[(size_t)rg * 256 + col]);
                        float u = tx + Hew[rg] * g * m;
                        if constexpr (XB) OutB[(size_t)tr * 256 + col] = f2bf(u);   // scatter into yb
                        else              OutB[(size_t)rg * 256 + col] = f2bf(u);
                    } else {
                        OutF[(size_t)rg * 256 + col] = fminf(fmaxf(z, 0.f), 1.f);
                    }
                }
            }
        }
    }
}

extern "C" void kernel_launch(void* const* d_in, const int* in_sizes, int n_in,
                              void* d_out, int out_size, void* d_ws, size_t ws_size,
                              hipStream_t stream) {
    const float* x      = (const float*)d_in[0];
    const int*   he_ptr = (const int*)d_in[1];
    const int*   he_src = (const int*)d_in[2];
    const int*   he_tgt = (const int*)d_in[3];
    const float* he_w   = (const float*)d_in[4];
    const float* W_msg  = (const float*)d_in[5];
    const float* b_msg  = (const float*)d_in[6];
    const float* W_gate = (const float*)d_in[7];
    const float* b_gate = (const float*)d_in[8];
    const float* W_upd  = (const float*)d_in[9];
    const float* b_upd  = (const float*)d_in[10];

    const int E = in_sizes[3];
    const int R = in_sizes[0] / H;

    const size_t wbytes = (size_t)(65536 + 131072 + 65536) * 2;
    const size_t needA = (size_t)R * H * 2 + (size_t)E * H * 2 * 2 + (size_t)R * 4 + wbytes;
    const bool bigws = ws_size >= needA;

    const int gE = (E + 127) / 128;
    const int gR = (R + 127) / 128;

    if (bigws) {
        char* ws = (char*)d_ws;
        ushort_t* yb   = (ushort_t*)ws;                                // R*256 bf16(x); becomes y after gemm2
        ushort_t* buf0 = yb + (size_t)R * H;                           // E*256: smb
        ushort_t* buf1 = buf0 + (size_t)E * H;                         // E*256: msgb
        ushort_t* Wmt  = (ushort_t*)(buf1 + (size_t)E * H);
        ushort_t* Wgt  = Wmt + 256 * 256;
        ushort_t* Wut  = Wgt + 256 * 512;

        prep_all<<<2048, 256, 0, stream>>>(W_msg, W_gate, W_upd, x,
                                           Wmt, Wgt, Wut, (int*)nullptr, yb, R, (size_t)R * H / 8);
        seg_mean_bf16<<<(E + 7) / 8, 256, 0, stream>>>(yb, he_ptr, he_src, buf0, E);

        // msg = smb @ Wm + b          (buf0 -> buf1)
        wgemm<0, 256, true><<<gE, 512, 0, stream>>>(buf0, nullptr, yb, nullptr, nullptr, nullptr,
                                                    Wmt, b_msg, buf1, nullptr, E);
        // gate + gated residual; u scattered into yb[tgt[e]]  -> yb becomes y
        wgemm<1, 512, true><<<gE, 512, 0, stream>>>(nullptr, nullptr, yb, buf1, he_tgt, he_w,
                                                    Wgt, b_gate, yb, nullptr, E);
        // out = clip(y @ Wu + b)      (yb linear -> d_out fp32)
        wgemm<3, 256, true><<<gR, 512, 0, stream>>>(yb, nullptr, nullptr, nullptr, nullptr, nullptr,
                                                    Wut, b_upd, nullptr, (float*)d_out, R);
    } else {
        char* ws = (char*)d_ws;
        ushort_t* buf0 = (ushort_t*)ws;
        ushort_t* buf1 = buf0 + (size_t)E * H;
        int*      imap = (int*)(buf1 + (size_t)E * H);
        ushort_t* Wmt  = (ushort_t*)((char*)imap + (size_t)R * 4);
        ushort_t* Wgt  = Wmt + 256 * 256;
        ushort_t* Wut  = Wgt + 256 * 512;

        prep_all<<<2048, 256, 0, stream>>>(W_msg, W_gate, W_upd, x,
                                           Wmt, Wgt, Wut, imap, (ushort_t*)nullptr, R, 0);
        imap_scatter<<<(E + 255) / 256, 256, 0, stream>>>(he_tgt, imap, E);
        seg_mean_f32w<<<(E + 3) / 4, 256, 0, stream>>>(x, he_ptr, he_src, buf0, E);

        wgemm<0, 256, false><<<gE, 512, 0, stream>>>(buf0, nullptr, nullptr, nullptr, nullptr, nullptr,
                                                     Wmt, b_msg, buf1, nullptr, E);
        wgemm<1, 512, false><<<gE, 512, 0, stream>>>(nullptr, x, nullptr, buf1, he_tgt, he_w,
                                                     Wgt, b_gate, buf0, nullptr, E);
        wgemm<2, 256, false><<<gR, 512, 0, stream>>>(nullptr, x, nullptr, buf0, imap, nullptr,
                                                     Wut, b_upd, nullptr, (float*)d_out, R);
    }
}